// Round 19
// baseline (368.735 us; speedup 1.0000x reference)
//
#include <hip/hip_runtime.h>
#include <hip/hip_bf16.h>

#define BT 2048
#define T_SEQ 1024
#define DIM 1024
#define DINNER 2048
#define DSTATE 128
#define HEADDIM 64
#define NHEADS 32
#define CONVCH 2304
#define DINPROJ 4384
#define EPS_F 1e-5f
#define NCHUNK 16   // T_SEQ / 64

typedef __bf16 bf16x8 __attribute__((ext_vector_type(8)));
typedef float f32x4 __attribute__((ext_vector_type(4)));

__device__ __forceinline__ float b2f(unsigned short u) {
  union { unsigned int i; float f; } v; v.i = ((unsigned int)u) << 16; return v.f;
}
__device__ __forceinline__ unsigned short f2b(float f) {
  unsigned int x = __float_as_uint(f);
  return (unsigned short)((x + 0x7fffu + ((x >> 16) & 1u)) >> 16);
}

// async global->LDS DMA (gemm staging)
__device__ __forceinline__ void gload_lds16(const void* g, void* l) {
  __builtin_amdgcn_global_load_lds(
      (const __attribute__((address_space(1))) unsigned int*)g,
      (__attribute__((address_space(3))) unsigned int*)l, 16, 0, 0);
}

// ---------------- fused prologue: 3x fp32->bf16 weight cvt + embed ----------
// r17-validated (-3 launches). r18: gw folded into Wo_b. r19: fnw (final
// RMSNorm gamma) folded into emb_b (emb_b is consumed only by gemm<2>;
// the embed-lookup branch reads raw emb).
#define NWP_ELEM (2 * DINPROJ * DIM)     // 8,978,432
#define NWO_ELEM (2 * DIM * DINNER)      // 4,194,304
#define NEM_ELEM (256 * DIM)             // 262,144
#define NWP_BLK (NWP_ELEM / 4 / 256)     // 8768
#define NWO_BLK (NWO_ELEM / 4 / 256)     // 4096
#define NEM_BLK (NEM_ELEM / 4 / 256)     // 256
#define PRO_BLK (NWP_BLK + NWO_BLK + NEM_BLK + BT)   // 15168

__global__ void prologue_k(const float* __restrict__ Wp, const float* __restrict__ Wo,
                           const float* __restrict__ emb, const float* __restrict__ gw,
                           const float* __restrict__ fnw,
                           unsigned short* __restrict__ Wp_b,
                           unsigned short* __restrict__ Wo_b,
                           unsigned short* __restrict__ emb_b,
                           const int* __restrict__ x,
                           float* __restrict__ h, unsigned short* __restrict__ hb) {
  int bid = blockIdx.x;
  if (bid < NWP_BLK) {
    int i = (bid * 256 + threadIdx.x) * 4;
    float4 v = *(const float4*)(Wp + i);
    Wp_b[i + 0] = f2b(v.x); Wp_b[i + 1] = f2b(v.y);
    Wp_b[i + 2] = f2b(v.z); Wp_b[i + 3] = f2b(v.w);
  } else if (bid < NWP_BLK + NWO_BLK) {
    int i = ((bid - NWP_BLK) * 256 + threadIdx.x) * 4;
    int li = i / (DIM * DINNER);
    int kk = i & (DINNER - 1);          // i % DINNER (i multiple of 4, no wrap)
    float4 v = *(const float4*)(Wo + i);
    float4 g = *(const float4*)(gw + li * DINNER + kk);
    Wo_b[i + 0] = f2b(v.x * g.x); Wo_b[i + 1] = f2b(v.y * g.y);
    Wo_b[i + 2] = f2b(v.z * g.z); Wo_b[i + 3] = f2b(v.w * g.w);
  } else if (bid < NWP_BLK + NWO_BLK + NEM_BLK) {
    int i = ((bid - NWP_BLK - NWO_BLK) * 256 + threadIdx.x) * 4;
    int kk = i & (DIM - 1);             // i % DIM (i multiple of 4, no wrap)
    float4 v = *(const float4*)(emb + i);
    float4 g = *(const float4*)(fnw + kk);
    emb_b[i + 0] = f2b(v.x * g.x); emb_b[i + 1] = f2b(v.y * g.y);
    emb_b[i + 2] = f2b(v.z * g.z); emb_b[i + 3] = f2b(v.w * g.w);
  } else {
    int t = bid - (NWP_BLK + NWO_BLK + NEM_BLK);
    int tok = x[t];
    int d = threadIdx.x;
#pragma unroll
    for (int j = 0; j < 4; ++j, d += 256) {
      float v = emb[(size_t)tok * DIM + d];
      h[(size_t)t * DIM + d] = v;
      hb[(size_t)t * DIM + d] = f2b(v);
    }
  }
}

// ---------------- GEMM: C[M,N] = A[M,K] * Bw[N,K]^T (bf16, fp32 acc) ----------------
// r9-validated structure (2-phase dbuf, BK=32; family closed). T1 XCD swizzle
// kept. r18: MODE==1 applies fused RMSNorm row-scale (ssq read) in the f32
// epilogue. r19: MODE==1 additionally accumulates ssqo[m] = sum_n h[m][n]^2
// (for the final norm); MODE==2 applies rsqrt(ssq[m]/DIM+eps) to the logits
// (fnw pre-folded into Bw=emb_b), replacing rmsfinal_k.
template <int MODE, int TM, int TN>
__global__ __launch_bounds__(256) void gemm_bt(
    const unsigned short* __restrict__ A,
    const unsigned short* __restrict__ Bw,
    int M, int N, int K,
    unsigned short* __restrict__ Cout,
    float* __restrict__ aux,
    unsigned short* __restrict__ aux2,
    const float* __restrict__ ssq,
    float* __restrict__ ssqo) {
  constexpr int FM = TM / 32, FN = TN / 32;
  constexpr int JA = TM / 64, JB = TN / 64;
  constexpr int HA = TM * 32, HB = TN * 32;   // elements per buffer
  __shared__ __align__(16) unsigned short As[2 * HA];
  __shared__ __align__(16) unsigned short Bs[2 * HB];
  const int tid = threadIdx.x;
  const int lane = tid & 63;
  const int wave = tid >> 6;

  // bijective XCD remap (m204): column-major chunks per XCD for B-panel L2 reuse.
  const int gx = gridDim.x, gy = gridDim.y;
  const int nwg = gx * gy;
  const int orig = (int)(blockIdx.y * gx + blockIdx.x);
  const int q = nwg >> 3, rr = nwg & 7;
  const int xcd = orig & 7, idx = orig >> 3;
  const int swz = (xcd < rr ? xcd * (q + 1) : rr * (q + 1) + (xcd - rr) * q) + idx;
  const int bxs = swz / gy;          // n-tile (column-major walk)
  const int bys = swz - bxs * gy;    // m-tile
  const int m0 = bys * TM;
  const int n0 = bxs * TN;

  const int wm = (wave >> 1) * (TM / 2);
  const int wn = (wave & 1) * (TN / 2);
  const int quad = lane >> 4;
  const int r = lane & 15;

  f32x4 acc[FM][FN];
#pragma unroll
  for (int i = 0; i < FM; ++i)
#pragma unroll
    for (int j = 0; j < FN; ++j) acc[i][j] = f32x4{0.f, 0.f, 0.f, 0.f};

  const int rowt = tid >> 2, colt = (tid & 3) * 8;
  const unsigned short* aG[JA];
  unsigned short* aD[JA];
  const unsigned short* bG[JB];
  unsigned short* bD[JB];
#pragma unroll
  for (int j = 0; j < JA; ++j) {
    aG[j] = A + (size_t)(m0 + rowt + j * 64) * K + colt;
    aD[j] = As + wave * 512 + j * 2048;
  }
#pragma unroll
  for (int j = 0; j < JB; ++j) {
    int rb = n0 + rowt + j * 64; if (rb >= N) rb = N - 1;
    bG[j] = Bw + (size_t)rb * K + colt;
    bD[j] = Bs + wave * 512 + j * 2048;
  }

  // prologue: stage K-tile 0 into buffer 0
#pragma unroll
  for (int j = 0; j < JA; ++j) gload_lds16(aG[j], aD[j]);
#pragma unroll
  for (int j = 0; j < JB; ++j) gload_lds16(bG[j], bD[j]);
  __syncthreads();   // drains vmcnt(0) -> buffer 0 visible

  int cur = 0;
  for (int k0 = 0; k0 < K; k0 += 32) {
    const int nxt = cur ^ 1;
    // issue prefetch of next K-tile into the other buffer (in flight during MFMA)
    if (k0 + 32 < K) {
#pragma unroll
      for (int j = 0; j < JA; ++j) gload_lds16(aG[j] + k0 + 32, aD[j] + nxt * HA);
#pragma unroll
      for (int j = 0; j < JB; ++j) gload_lds16(bG[j] + k0 + 32, bD[j] + nxt * HB);
    }
    const bf16x8* ap = (const bf16x8*)(As + cur * HA);
    const bf16x8* bp = (const bf16x8*)(Bs + cur * HB);
    bf16x8 af[FM], bfr[FN];
#pragma unroll
    for (int mt = 0; mt < FM; ++mt) af[mt] = ap[(wm + mt * 16 + r) * 4 + quad];
#pragma unroll
    for (int nt = 0; nt < FN; ++nt) bfr[nt] = bp[(wn + nt * 16 + r) * 4 + quad];
#pragma unroll
    for (int mt = 0; mt < FM; ++mt)
#pragma unroll
      for (int nt = 0; nt < FN; ++nt)
        acc[mt][nt] = __builtin_amdgcn_mfma_f32_16x16x32_bf16(af[mt], bfr[nt], acc[mt][nt], 0, 0, 0);
    __syncthreads();  // drains prefetch (hidden under MFMA) + read-done fence
    cur = nxt;
  }

  float rs[FM][4];
  if (MODE == 1) {
#pragma unroll
    for (int mt = 0; mt < FM; ++mt)
#pragma unroll
      for (int i = 0; i < 4; ++i) rs[mt][i] = 0.f;
  }

#pragma unroll
  for (int mt = 0; mt < FM; ++mt) {
#pragma unroll
    for (int nt = 0; nt < FN; ++nt) {
#pragma unroll
      for (int i = 0; i < 4; ++i) {
        int gm = m0 + wm + mt * 16 + quad * 4 + i;
        int gn = n0 + wn + nt * 16 + r;
        if (gn < N) {
          float v = acc[mt][nt][i];
          if (MODE == 0) {
            Cout[(size_t)gm * N + gn] = f2b(v);
            if (gn >= DINNER + CONVCH)
              aux[(size_t)gm * NHEADS + (gn - (DINNER + CONVCH))] = v;
          } else if (MODE == 1) {
            float scl = rsqrtf(ssq[gm] * (1.f / DINNER) + EPS_F);
            size_t o = (size_t)gm * N + gn;
            float hnv = aux[o] + v * scl;
            aux[o] = hnv;
            aux2[o] = f2b(hnv);
            rs[mt][i] += hnv * hnv;
          } else {
            float scl = rsqrtf(ssq[gm] * (1.f / DIM) + EPS_F);
            aux[(size_t)gm * N + gn] = v * scl;
          }
        }
      }
    }
  }

  if (MODE == 1) {
    // per-row partial sum of h^2 over this block's 64 columns -> atomic
#pragma unroll
    for (int mt = 0; mt < FM; ++mt)
#pragma unroll
      for (int i = 0; i < 4; ++i) {
        float s = rs[mt][i];
        s += __shfl_xor(s, 1, 64);
        s += __shfl_xor(s, 2, 64);
        s += __shfl_xor(s, 4, 64);
        s += __shfl_xor(s, 8, 64);
        if (r == 0) {
          int gm = m0 + wm + mt * 16 + quad * 4 + i;
          atomicAdd(&ssqo[gm], s);
        }
      }
  }
}

// ---------------- causal conv (K=4) + silu, with fused dt/lnA ----------------
// r9 scalar form (measured best). r18/r19: zeroes ssq[t] and ssqh[t] for the
// fused norms (safe: runs after the previous consumers of both).
__global__ void conv_k(const unsigned short* __restrict__ zx,
                       const float* __restrict__ cw,
                       const float* __restrict__ cb,
                       unsigned short* __restrict__ xbc,
                       unsigned short* __restrict__ bcb,
                       const float* __restrict__ dtraw,
                       const float* __restrict__ dtb,
                       const float* __restrict__ alog,
                       float* __restrict__ dtf,
                       float* __restrict__ lnAf,
                       float* __restrict__ ssq,
                       float* __restrict__ ssqh) {
  int t = blockIdx.x;
  int tt = t & (T_SEQ - 1);
  if (threadIdx.x == 0) ssq[t] = 0.f;
  if (threadIdx.x == 1) ssqh[t] = 0.f;
  if (threadIdx.x < NHEADS) {
    int h = threadIdx.x;
    float xx = dtraw[t * NHEADS + h] + dtb[h];
    float sp = (xx > 20.f) ? xx : log1pf(expf(xx));
    dtf[t * NHEADS + h] = sp;
    lnAf[t * NHEADS + h] = -sp * expf(alog[h]);
  }
  for (int c = threadIdx.x; c < CONVCH; c += 256) {
    float acc = cb[c];
#pragma unroll
    for (int k = 0; k < 4; ++k) {
      int tp = tt - 3 + k;
      if (tp >= 0)
        acc += b2f(zx[(size_t)(t - 3 + k) * DINPROJ + DINNER + c]) * cw[c * 4 + k];
    }
    float s = acc / (1.f + expf(-acc));
    unsigned short sb = f2b(s);
    xbc[(size_t)t * CONVCH + c] = sb;
    if (c >= DINNER) bcb[(size_t)t * 256 + (c - DINNER)] = sb;
  }
}

// ---------------- SSD pass 1: intra-chunk (per (b,h,chunk)) ----------------
// r8 (validated): wsL precompute + BWT cooperative transpose.
__global__ __launch_bounds__(256) void ssd_intra(
    const unsigned short* __restrict__ bcb,
    const unsigned short* __restrict__ xbc,
    const float* __restrict__ dtf, const float* __restrict__ lnAf,
    unsigned short* __restrict__ y1buf, unsigned short* __restrict__ SL,
    float* __restrict__ dtot) {
  const int bi = blockIdx.x;           // ((b*32+h)*16 + c), 1024 blocks
  const int c = bi & 15;
  const int h = (bi >> 4) & 31;
  const int b = bi >> 9;
  const int tid = threadIdx.x;
  const int w = tid >> 6, l = tid & 63, r = l & 15, quad = l >> 4;
  const size_t tok0 = (size_t)b * T_SEQ + c * 64;

  __shared__ __align__(16) unsigned short BCs[64 * 264];  // [t][B0..127|C128..255]+pad
  __shared__ __align__(16) unsigned short Xrow[64 * 72];  // [u][p]
  __shared__ __align__(16) unsigned short XTs[64 * 72];   // [p][u]
  __shared__ __align__(16) unsigned short BWT[128 * 72];  // [n][u] = ws[u]*B[u][n]
  __shared__ __align__(16) unsigned short Ms[64 * 72];    // [t][u]
  __shared__ float cumL[64], dtL[64], wsL[64];

#pragma unroll
  for (int i = 0; i < 8; ++i) {
    int idx = tid + i * 256;
    int row = idx >> 5, col = (idx & 31) * 8;
    uint4 v = *(const uint4*)(bcb + (tok0 + row) * 256 + col);
    *(uint4*)(BCs + row * 264 + col) = v;
  }
  // x tile: rows = tokens (coalesced 128B from xbc), cols = p
#pragma unroll
  for (int i = 0; i < 2; ++i) {
    int idx = tid + i * 256;
    int u = idx >> 3, pc = (idx & 7) * 8;
    uint4 v = *(const uint4*)(xbc + (tok0 + u) * CONVCH + h * HEADDIM + pc);
    *(uint4*)(Xrow + u * 72 + pc) = v;
  }
  if (tid < 64) {
    float dt = dtf[(tok0 + tid) * NHEADS + h];
    float v = lnAf[(tok0 + tid) * NHEADS + h];
    dtL[tid] = dt;
#pragma unroll
    for (int off = 1; off < 64; off <<= 1) {
      float u = __shfl_up(v, off, 64);
      if (tid >= off) v += u;
    }
    cumL[tid] = v;
    float tot = __shfl(v, 63, 64);   // scan total, in-wave broadcast
    wsL[tid] = dt * expf(tot - v);   // ws[u] = dt[u]*exp(cum63-cum[u]), once
    if (tid == 63) dtot[bi] = expf(tot);
  }
  __syncthreads();

  // in-LDS transpose: XTs[p][u] = x
#pragma unroll
  for (int i = 0; i < 2; ++i) {
    int idx = tid + i * 256;
    int p = idx >> 3, ug = (idx & 7) * 8;
    unsigned short tA[8];
#pragma unroll
    for (int j = 0; j < 8; ++j) tA[j] = Xrow[(ug + j) * 72 + p];
    *(uint4*)(XTs + p * 72 + ug) = *(uint4*)tA;
  }

  // cooperative B-transpose with ws fold: BWT[n][u] = ws[u]*B[u][n]
  {
    const int n = tid >> 1;
    const int ug = (tid & 1) * 32;
    unsigned short eb[32];
#pragma unroll
    for (int j = 0; j < 32; ++j)
      eb[j] = f2b(b2f(BCs[(ug + j) * 264 + n]) * wsL[ug + j]);
#pragma unroll
    for (int qq = 0; qq < 4; ++qq)
      *(uint4*)(BWT + n * 72 + ug + qq * 8) = *(uint4*)(eb + qq * 8);
  }

  // GEMM1: G = C·B^T  (64x64, K=128)
  f32x4 g[4];
#pragma unroll
  for (int nt = 0; nt < 4; ++nt) g[nt] = f32x4{0.f, 0.f, 0.f, 0.f};
#pragma unroll
  for (int kk = 0; kk < 4; ++kk) {
    bf16x8 afr = *(const bf16x8*)(BCs + (w * 16 + r) * 264 + 128 + kk * 32 + quad * 8);
#pragma unroll
    for (int nt = 0; nt < 4; ++nt) {
      bf16x8 bfr = *(const bf16x8*)(BCs + (nt * 16 + r) * 264 + kk * 32 + quad * 8);
      g[nt] = __builtin_amdgcn_mfma_f32_16x16x32_bf16(afr, bfr, g[nt], 0, 0, 0);
    }
  }
#pragma unroll
  for (int nt = 0; nt < 4; ++nt) {
#pragma unroll
    for (int i = 0; i < 4; ++i) {
      int t_ = w * 16 + quad * 4 + i;
      int u_ = nt * 16 + r;
      float wv = (u_ <= t_) ? expf(cumL[t_] - cumL[u_]) * dtL[u_] : 0.f;
      Ms[t_ * 72 + u_] = f2b(g[nt][i] * wv);
    }
  }
  __syncthreads();   // fences Ms, XTs, BWT writes -> GEMM2/GEMM3 reads

  // GEMM2: Y1 = M·X  (64t x 64p, K=64u)
  f32x4 y1[4];
#pragma unroll
  for (int nt = 0; nt < 4; ++nt) y1[nt] = f32x4{0.f, 0.f, 0.f, 0.f};
#pragma unroll
  for (int kk = 0; kk < 2; ++kk) {
    bf16x8 afr = *(const bf16x8*)(Ms + (w * 16 + r) * 72 + kk * 32 + quad * 8);
#pragma unroll
    for (int nt = 0; nt < 4; ++nt) {
      bf16x8 bfr = *(const bf16x8*)(XTs + (nt * 16 + r) * 72 + kk * 32 + quad * 8);
      y1[nt] = __builtin_amdgcn_mfma_f32_16x16x32_bf16(afr, bfr, y1[nt], 0, 0, 0);
    }
  }
#pragma unroll
  for (int nt = 0; nt < 4; ++nt)
#pragma unroll
    for (int i = 0; i < 4; ++i) {
      int t_ = w * 16 + quad * 4 + i, p_ = nt * 16 + r;
      y1buf[((size_t)bi * 64 + t_) * 64 + p_] = f2b(y1[nt][i]);
    }

  // GEMM3: Slocal[p][n] = sum_u XTs[p][u] * BWT[n][u]  (64p x 128n, K=64u)
  f32x4 sl[8];
#pragma unroll
  for (int nt = 0; nt < 8; ++nt) sl[nt] = f32x4{0.f, 0.f, 0.f, 0.f};
#pragma unroll
  for (int kk = 0; kk < 2; ++kk) {
    bf16x8 afr = *(const bf16x8*)(XTs + (w * 16 + r) * 72 + kk * 32 + quad * 8);
#pragma unroll
    for (int nt = 0; nt < 8; ++nt) {
      bf16x8 bfr = *(const bf16x8*)(BWT + (nt * 16 + r) * 72 + kk * 32 + quad * 8);
      sl[nt] = __builtin_amdgcn_mfma_f32_16x16x32_bf16(afr, bfr, sl[nt], 0, 0, 0);
    }
  }
#pragma unroll
  for (int nt = 0; nt < 8; ++nt)
#pragma unroll
    for (int i = 0; i < 4; ++i) {
      int p_ = w * 16 + quad * 4 + i, n_ = nt * 16 + r;
      SL[((size_t)bi * 64 + p_) * 128 + n_] = f2b(sl[nt][i]);
    }
}

// ---------------- SSD pass 2: chunk-state recurrence (in-place Slocal -> Spre) --------
__global__ void ssd_state(unsigned short* __restrict__ SL,
                          const float* __restrict__ dtot) {
  int gidx = blockIdx.x * 256 + threadIdx.x;   // 131072 = 64bh * 64p * 32(n/4)
  int n4 = (gidx & 31) * 4;
  int p = (gidx >> 5) & 63;
  int bh = gidx >> 11;
  float sx = 0.f, sy = 0.f, sz = 0.f, sw = 0.f;
  for (int c = 0; c < NCHUNK; ++c) {
    size_t off = ((size_t)(bh * 16 + c) * 64 + p) * 128 + n4;
    uint2 lv = *(uint2*)(SL + off);
    float d = dtot[bh * 16 + c];
    uint2 sv;
    sv.x = (unsigned)f2b(sx) | ((unsigned)f2b(sy) << 16);
    sv.y = (unsigned)f2b(sz) | ((unsigned)f2b(sw) << 16);
    *(uint2*)(SL + off) = sv;           // state BEFORE chunk c
    sx = d * sx + b2f(lv.x & 0xffff);
    sy = d * sy + b2f(lv.x >> 16);
    sz = d * sz + b2f(lv.y & 0xffff);
    sw = d * sw + b2f(lv.y >> 16);
  }
}

// ---------------- SSD pass 3: inter-chunk + combine + gate ----------------
// r18: accumulates per-token sum-of-squares of the gated f32 output into
// ssq[tok] for the fused RMSNorm in gemm<1>'s epilogue.
__global__ __launch_bounds__(256) void ssd_inter(
    const unsigned short* __restrict__ bcb,
    const unsigned short* __restrict__ SL,       // holds Spre now
    const unsigned short* __restrict__ y1buf,
    const unsigned short* __restrict__ xbc,
    const unsigned short* __restrict__ zx,
    const float* __restrict__ lnAf,
    const float* __restrict__ Dw,
    unsigned short* __restrict__ yg,
    float* __restrict__ ssq) {
  const int bi = blockIdx.x;
  const int c = bi & 15, h = (bi >> 4) & 31, b = bi >> 9;
  const int tid = threadIdx.x;
  const int w = tid >> 6, l = tid & 63, r = l & 15, quad = l >> 4;
  const size_t tok0 = (size_t)b * T_SEQ + c * 64;

  __shared__ __align__(16) unsigned short Cs[64 * 136];
  __shared__ __align__(16) unsigned short Sp[64 * 136];
  __shared__ __align__(16) float Yf[64 * 68];
  __shared__ float cumL[64];

#pragma unroll
  for (int i = 0; i < 4; ++i) {
    int idx = tid + i * 256;
    int row = idx >> 4, col = (idx & 15) * 8;
    uint4 v = *(const uint4*)(bcb + (tok0 + row) * 256 + 128 + col);
    *(uint4*)(Cs + row * 136 + col) = v;
    uint4 s = *(const uint4*)(SL + ((size_t)bi * 64 + row) * 128 + col);
    *(uint4*)(Sp + row * 136 + col) = s;
  }
  if (tid < 64) {
    float v = lnAf[(tok0 + tid) * NHEADS + h];
#pragma unroll
    for (int off = 1; off < 64; off <<= 1) {
      float u = __shfl_up(v, off, 64);
      if (tid >= off) v += u;
    }
    cumL[tid] = v;
  }
  __syncthreads();

  // Yi[t][p] = sum_n C[t][n]*Spre[p][n]  (K=128)
  f32x4 yi[4];
#pragma unroll
  for (int nt = 0; nt < 4; ++nt) yi[nt] = f32x4{0.f, 0.f, 0.f, 0.f};
#pragma unroll
  for (int kk = 0; kk < 4; ++kk) {
    bf16x8 afr = *(const bf16x8*)(Cs + (w * 16 + r) * 136 + kk * 32 + quad * 8);
#pragma unroll
    for (int nt = 0; nt < 4; ++nt) {
      bf16x8 bfr = *(const bf16x8*)(Sp + (nt * 16 + r) * 136 + kk * 32 + quad * 8);
      yi[nt] = __builtin_amdgcn_mfma_f32_16x16x32_bf16(afr, bfr, yi[nt], 0, 0, 0);
    }
  }
#pragma unroll
  for (int nt = 0; nt < 4; ++nt)
#pragma unroll
    for (int i = 0; i < 4; ++i) {
      int t_ = w * 16 + quad * 4 + i, p_ = nt * 16 + r;
      float y1 = b2f(y1buf[((size_t)bi * 64 + t_) * 64 + p_]);
      Yf[t_ * 68 + p_] = y1 + expf(cumL[t_]) * yi[nt][i];
    }
  __syncthreads();

  // combine: y = Yf + D*x, gate with silu(z), write yg + accumulate ssq
  const float Dh = Dw[h];
  const int t_ = tid >> 2, pg = (tid & 3) * 16;
  const size_t tok = tok0 + t_;
  union { uint4 q[2]; unsigned short u[16]; } xv, zv, ov;
  xv.q[0] = *(const uint4*)(xbc + tok * CONVCH + h * 64 + pg);
  xv.q[1] = *(const uint4*)(xbc + tok * CONVCH + h * 64 + pg + 8);
  zv.q[0] = *(const uint4*)(zx + tok * DINPROJ + h * 64 + pg);
  zv.q[1] = *(const uint4*)(zx + tok * DINPROJ + h * 64 + pg + 8);
  float ssf = 0.f;
#pragma unroll
  for (int j = 0; j < 16; ++j) {
    float y = Yf[t_ * 68 + pg + j] + Dh * b2f(xv.u[j]);
    float zf = b2f(zv.u[j]);
    float yg_f = y * (zf / (1.f + expf(-zf)));
    ov.u[j] = f2b(yg_f);
    ssf += yg_f * yg_f;
  }
  *(uint4*)(yg + tok * DINNER + h * 64 + pg) = ov.q[0];
  *(uint4*)(yg + tok * DINNER + h * 64 + pg + 8) = ov.q[1];
  // reduce the 4 lanes of this token, one atomic per token per block
  ssf += __shfl_xor(ssf, 1, 64);
  ssf += __shfl_xor(ssf, 2, 64);
  if ((tid & 3) == 0) atomicAdd(&ssq[tok], ssf);
}

extern "C" void kernel_launch(void* const* d_in, const int* in_sizes, int n_in,
                              void* d_out, int out_size, void* d_ws, size_t ws_size,
                              hipStream_t stream) {
  const int*   x    = (const int*)d_in[0];
  const float* emb  = (const float*)d_in[1];
  const float* Wp   = (const float*)d_in[2];
  const float* cw   = (const float*)d_in[3];
  const float* cb   = (const float*)d_in[4];
  const float* dtb  = (const float*)d_in[5];
  const float* alog = (const float*)d_in[6];
  const float* Dw   = (const float*)d_in[7];
  const float* gw   = (const float*)d_in[8];
  const float* Wo   = (const float*)d_in[9];
  const float* fnw  = (const float*)d_in[10];

  char* w = (char*)d_ws;
  auto alloc = [&](size_t bytes) {
    char* p = w; w += (bytes + 255) & ~(size_t)255; return p;
  };
  float* h_f32          = (float*)alloc((size_t)BT * DIM * 4);
  unsigned short* hb    = (unsigned short*)alloc((size_t)BT * DIM * 2);
  unsigned short* zx    = (unsigned short*)alloc((size_t)BT * DINPROJ * 2);
  float* dtraw          = (float*)alloc((size_t)BT * NHEADS * 4);
  float* dtf            = (float*)alloc((size_t)BT * NHEADS * 4);
  float* lnAf           = (float*)alloc((size_t)BT * NHEADS * 4);
  unsigned short* xbc   = (unsigned short*)alloc((size_t)BT * CONVCH * 2);
  unsigned short* bcb   = (unsigned short*)alloc((size_t)BT * 256 * 2);
  unsigned short* SL    = (unsigned short*)alloc((size_t)1024 * 64 * 128 * 2);
  unsigned short* y1buf = (unsigned short*)alloc((size_t)1024 * 64 * 64 * 2);
  float* dtot           = (float*)alloc((size_t)1024 * 4);
  unsigned short* yg    = (unsigned short*)alloc((size_t)BT * DINNER * 2);
  float* ssq            = (float*)alloc((size_t)BT * 4);
  float* ssqh           = (float*)alloc((size_t)BT * 4);
  unsigned short* Wp_b  = (unsigned short*)alloc((size_t)2 * DINPROJ * DIM * 2);
  unsigned short* Wo_b  = (unsigned short*)alloc((size_t)2 * DIM * DINNER * 2);
  unsigned short* emb_b = (unsigned short*)alloc((size_t)256 * DIM * 2 + 256);

  // fused prologue: 3x weight cvt (gw->Wo_b, fnw->emb_b) + embed in ONE launch
  prologue_k<<<PRO_BLK, 256, 0, stream>>>(Wp, Wo, emb, gw, fnw, Wp_b, Wo_b, emb_b, x, h_f32, hb);

  for (int l = 0; l < 2; ++l) {
    const unsigned short* Wpl = Wp_b + (size_t)l * DINPROJ * DIM;
    const unsigned short* Wol = Wo_b + (size_t)l * DIM * DINNER;
    const float* cwl   = cw + (size_t)l * CONVCH * 4;
    const float* cbl   = cb + (size_t)l * CONVCH;
    const float* dtbl  = dtb + l * NHEADS;
    const float* alogl = alog + l * NHEADS;
    const float* Dwl   = Dw + l * NHEADS;

    gemm_bt<0, 128, 128><<<dim3(35, 16), 256, 0, stream>>>(hb, Wpl, BT, DINPROJ, DIM, zx, dtraw, nullptr, nullptr, nullptr);
    conv_k<<<BT, 256, 0, stream>>>(zx, cwl, cbl, xbc, bcb, dtraw, dtbl, alogl, dtf, lnAf, ssq, ssqh);
    ssd_intra<<<1024, 256, 0, stream>>>(bcb, xbc, dtf, lnAf, y1buf, SL, dtot);
    ssd_state<<<512, 256, 0, stream>>>(SL, dtot);
    ssd_inter<<<1024, 256, 0, stream>>>(bcb, SL, y1buf, xbc, zx, lnAf, Dwl, yg, ssq);
    gemm_bt<1, 64, 64><<<dim3(16, 32), 256, 0, stream>>>(yg, Wol, BT, DIM, DINNER, nullptr, h_f32, hb, ssq, ssqh);
  }

  // final norm fused into the logits GEMM: A = un-normalized bf16 h (hb),
  // row-scale from ssqh in the epilogue, fnw pre-folded into emb_b.
  gemm_bt<2, 64, 64><<<dim3(4, 32), 256, 0, stream>>>(hb, emb_b, BT, 256, DIM,
                                                      nullptr, (float*)d_out, nullptr, ssqh, nullptr);
}

// Round 20
// 365.450 us; speedup vs baseline: 1.0090x; 1.0090x over previous
//
#include <hip/hip_runtime.h>
#include <hip/hip_bf16.h>

#define BT 2048
#define T_SEQ 1024
#define DIM 1024
#define DINNER 2048
#define DSTATE 128
#define HEADDIM 64
#define NHEADS 32
#define CONVCH 2304
#define DINPROJ 4384
#define EPS_F 1e-5f
#define NCHUNK 16   // T_SEQ / 64

typedef __bf16 bf16x8 __attribute__((ext_vector_type(8)));
typedef float f32x4 __attribute__((ext_vector_type(4)));

__device__ __forceinline__ float b2f(unsigned short u) {
  union { unsigned int i; float f; } v; v.i = ((unsigned int)u) << 16; return v.f;
}
__device__ __forceinline__ unsigned short f2b(float f) {
  unsigned int x = __float_as_uint(f);
  return (unsigned short)((x + 0x7fffu + ((x >> 16) & 1u)) >> 16);
}

// async global->LDS DMA (gemm staging)
__device__ __forceinline__ void gload_lds16(const void* g, void* l) {
  __builtin_amdgcn_global_load_lds(
      (const __attribute__((address_space(1))) unsigned int*)g,
      (__attribute__((address_space(3))) unsigned int*)l, 16, 0, 0);
}

// ---------------- fused prologue: 3x fp32->bf16 weight cvt + embed ----------
// r17-validated (-3 launches, ~6us). r18: Wo conversion additionally folds
// gnorm_w (RMSNorm gamma) into Wo_b: Wo_fold[l][n][k] = Wo[l][n][k]*gw[l][k]
// -- part of the rms2048 algebraic fusion (scale factors out of the GEMM,
// gamma folds into the weight). r19's rmsfinal fusion REVERTED: the added
// per-row reduce trees in gemm<1>'s latency-bound epilogue cost more (+5us)
// than the saved launch+body (~4us). Norm fusion pays only when the producer
// kernel's layout makes the reduction nearly free (ssd_inter: 2 shfl/token).
#define NWP_ELEM (2 * DINPROJ * DIM)     // 8,978,432
#define NWO_ELEM (2 * DIM * DINNER)      // 4,194,304
#define NEM_ELEM (256 * DIM)             // 262,144
#define NWP_BLK (NWP_ELEM / 4 / 256)     // 8768
#define NWO_BLK (NWO_ELEM / 4 / 256)     // 4096
#define NEM_BLK (NEM_ELEM / 4 / 256)     // 256
#define PRO_BLK (NWP_BLK + NWO_BLK + NEM_BLK + BT)   // 15168

__global__ void prologue_k(const float* __restrict__ Wp, const float* __restrict__ Wo,
                           const float* __restrict__ emb, const float* __restrict__ gw,
                           unsigned short* __restrict__ Wp_b,
                           unsigned short* __restrict__ Wo_b,
                           unsigned short* __restrict__ emb_b,
                           const int* __restrict__ x,
                           float* __restrict__ h, unsigned short* __restrict__ hb) {
  int bid = blockIdx.x;
  if (bid < NWP_BLK) {
    int i = (bid * 256 + threadIdx.x) * 4;
    float4 v = *(const float4*)(Wp + i);
    Wp_b[i + 0] = f2b(v.x); Wp_b[i + 1] = f2b(v.y);
    Wp_b[i + 2] = f2b(v.z); Wp_b[i + 3] = f2b(v.w);
  } else if (bid < NWP_BLK + NWO_BLK) {
    int i = ((bid - NWP_BLK) * 256 + threadIdx.x) * 4;
    int li = i / (DIM * DINNER);
    int kk = i & (DINNER - 1);          // i % DINNER (i multiple of 4, no wrap)
    float4 v = *(const float4*)(Wo + i);
    float4 g = *(const float4*)(gw + li * DINNER + kk);
    Wo_b[i + 0] = f2b(v.x * g.x); Wo_b[i + 1] = f2b(v.y * g.y);
    Wo_b[i + 2] = f2b(v.z * g.z); Wo_b[i + 3] = f2b(v.w * g.w);
  } else if (bid < NWP_BLK + NWO_BLK + NEM_BLK) {
    int i = ((bid - NWP_BLK - NWO_BLK) * 256 + threadIdx.x) * 4;
    float4 v = *(const float4*)(emb + i);
    emb_b[i + 0] = f2b(v.x); emb_b[i + 1] = f2b(v.y);
    emb_b[i + 2] = f2b(v.z); emb_b[i + 3] = f2b(v.w);
  } else {
    int t = bid - (NWP_BLK + NWO_BLK + NEM_BLK);
    int tok = x[t];
    int d = threadIdx.x;
#pragma unroll
    for (int j = 0; j < 4; ++j, d += 256) {
      float v = emb[(size_t)tok * DIM + d];
      h[(size_t)t * DIM + d] = v;
      hb[(size_t)t * DIM + d] = f2b(v);
    }
  }
}

// ---------------- GEMM: C[M,N] = A[M,K] * Bw[N,K]^T (bf16, fp32 acc) ----------------
// r9-validated structure (2-phase dbuf, BK=32; family closed, see r3/r4/r7/r10
// brackets). T1 XCD column-major swizzle kept. r18: MODE==1 applies the fused
// RMSNorm row-scale rsqrt(ssq[m]/DINNER+eps) in the f32 epilogue (A = yg
// un-normalized; gamma pre-folded into Bw).
template <int MODE, int TM, int TN>
__global__ __launch_bounds__(256) void gemm_bt(
    const unsigned short* __restrict__ A,
    const unsigned short* __restrict__ Bw,
    int M, int N, int K,
    unsigned short* __restrict__ Cout,
    float* __restrict__ aux,
    unsigned short* __restrict__ aux2,
    const float* __restrict__ ssq) {
  constexpr int FM = TM / 32, FN = TN / 32;
  constexpr int JA = TM / 64, JB = TN / 64;
  constexpr int HA = TM * 32, HB = TN * 32;   // elements per buffer
  __shared__ __align__(16) unsigned short As[2 * HA];
  __shared__ __align__(16) unsigned short Bs[2 * HB];
  const int tid = threadIdx.x;
  const int lane = tid & 63;
  const int wave = tid >> 6;

  // bijective XCD remap (m204): column-major chunks per XCD for B-panel L2 reuse.
  const int gx = gridDim.x, gy = gridDim.y;
  const int nwg = gx * gy;
  const int orig = (int)(blockIdx.y * gx + blockIdx.x);
  const int q = nwg >> 3, rr = nwg & 7;
  const int xcd = orig & 7, idx = orig >> 3;
  const int swz = (xcd < rr ? xcd * (q + 1) : rr * (q + 1) + (xcd - rr) * q) + idx;
  const int bxs = swz / gy;          // n-tile (column-major walk)
  const int bys = swz - bxs * gy;    // m-tile
  const int m0 = bys * TM;
  const int n0 = bxs * TN;

  const int wm = (wave >> 1) * (TM / 2);
  const int wn = (wave & 1) * (TN / 2);
  const int quad = lane >> 4;
  const int r = lane & 15;

  f32x4 acc[FM][FN];
#pragma unroll
  for (int i = 0; i < FM; ++i)
#pragma unroll
    for (int j = 0; j < FN; ++j) acc[i][j] = f32x4{0.f, 0.f, 0.f, 0.f};

  const int rowt = tid >> 2, colt = (tid & 3) * 8;
  const unsigned short* aG[JA];
  unsigned short* aD[JA];
  const unsigned short* bG[JB];
  unsigned short* bD[JB];
#pragma unroll
  for (int j = 0; j < JA; ++j) {
    aG[j] = A + (size_t)(m0 + rowt + j * 64) * K + colt;
    aD[j] = As + wave * 512 + j * 2048;
  }
#pragma unroll
  for (int j = 0; j < JB; ++j) {
    int rb = n0 + rowt + j * 64; if (rb >= N) rb = N - 1;
    bG[j] = Bw + (size_t)rb * K + colt;
    bD[j] = Bs + wave * 512 + j * 2048;
  }

  // prologue: stage K-tile 0 into buffer 0
#pragma unroll
  for (int j = 0; j < JA; ++j) gload_lds16(aG[j], aD[j]);
#pragma unroll
  for (int j = 0; j < JB; ++j) gload_lds16(bG[j], bD[j]);
  __syncthreads();   // drains vmcnt(0) -> buffer 0 visible

  int cur = 0;
  for (int k0 = 0; k0 < K; k0 += 32) {
    const int nxt = cur ^ 1;
    // issue prefetch of next K-tile into the other buffer (in flight during MFMA)
    if (k0 + 32 < K) {
#pragma unroll
      for (int j = 0; j < JA; ++j) gload_lds16(aG[j] + k0 + 32, aD[j] + nxt * HA);
#pragma unroll
      for (int j = 0; j < JB; ++j) gload_lds16(bG[j] + k0 + 32, bD[j] + nxt * HB);
    }
    const bf16x8* ap = (const bf16x8*)(As + cur * HA);
    const bf16x8* bp = (const bf16x8*)(Bs + cur * HB);
    bf16x8 af[FM], bfr[FN];
#pragma unroll
    for (int mt = 0; mt < FM; ++mt) af[mt] = ap[(wm + mt * 16 + r) * 4 + quad];
#pragma unroll
    for (int nt = 0; nt < FN; ++nt) bfr[nt] = bp[(wn + nt * 16 + r) * 4 + quad];
#pragma unroll
    for (int mt = 0; mt < FM; ++mt)
#pragma unroll
      for (int nt = 0; nt < FN; ++nt)
        acc[mt][nt] = __builtin_amdgcn_mfma_f32_16x16x32_bf16(af[mt], bfr[nt], acc[mt][nt], 0, 0, 0);
    __syncthreads();  // drains prefetch (hidden under MFMA) + read-done fence
    cur = nxt;
  }

#pragma unroll
  for (int mt = 0; mt < FM; ++mt) {
#pragma unroll
    for (int nt = 0; nt < FN; ++nt) {
#pragma unroll
      for (int i = 0; i < 4; ++i) {
        int gm = m0 + wm + mt * 16 + quad * 4 + i;
        int gn = n0 + wn + nt * 16 + r;
        if (gn < N) {
          float v = acc[mt][nt][i];
          if (MODE == 0) {
            Cout[(size_t)gm * N + gn] = f2b(v);
            if (gn >= DINNER + CONVCH)
              aux[(size_t)gm * NHEADS + (gn - (DINNER + CONVCH))] = v;
          } else if (MODE == 1) {
            float scl = rsqrtf(ssq[gm] * (1.f / DINNER) + EPS_F);
            size_t o = (size_t)gm * N + gn;
            float hnv = aux[o] + v * scl;
            aux[o] = hnv;
            aux2[o] = f2b(hnv);
          } else {
            aux[(size_t)gm * N + gn] = v;
          }
        }
      }
    }
  }
}

// ---------------- causal conv (K=4) + silu, with fused dt/lnA ----------------
// r9 scalar form (measured best; r11 vectorization was neutral). r18: thread 0
// zeroes ssq[t] for the fused RMSNorm accumulation (safe: runs after the
// previous layer's gemm<1> consumed ssq, before this layer's ssd_inter).
__global__ void conv_k(const unsigned short* __restrict__ zx,
                       const float* __restrict__ cw,
                       const float* __restrict__ cb,
                       unsigned short* __restrict__ xbc,
                       unsigned short* __restrict__ bcb,
                       const float* __restrict__ dtraw,
                       const float* __restrict__ dtb,
                       const float* __restrict__ alog,
                       float* __restrict__ dtf,
                       float* __restrict__ lnAf,
                       float* __restrict__ ssq) {
  int t = blockIdx.x;
  int tt = t & (T_SEQ - 1);
  if (threadIdx.x == 0) ssq[t] = 0.f;
  if (threadIdx.x < NHEADS) {
    int h = threadIdx.x;
    float xx = dtraw[t * NHEADS + h] + dtb[h];
    float sp = (xx > 20.f) ? xx : log1pf(expf(xx));
    dtf[t * NHEADS + h] = sp;
    lnAf[t * NHEADS + h] = -sp * expf(alog[h]);
  }
  for (int c = threadIdx.x; c < CONVCH; c += 256) {
    float acc = cb[c];
#pragma unroll
    for (int k = 0; k < 4; ++k) {
      int tp = tt - 3 + k;
      if (tp >= 0)
        acc += b2f(zx[(size_t)(t - 3 + k) * DINPROJ + DINNER + c]) * cw[c * 4 + k];
    }
    float s = acc / (1.f + expf(-acc));
    unsigned short sb = f2b(s);
    xbc[(size_t)t * CONVCH + c] = sb;
    if (c >= DINNER) bcb[(size_t)t * 256 + (c - DINNER)] = sb;
  }
}

// ---------------- SSD pass 1: intra-chunk (per (b,h,chunk)) ----------------
// r8 (validated, 377us): wsL precompute + BWT cooperative transpose; GEMM3
// is ds_read_b128 on both operands.
__global__ __launch_bounds__(256) void ssd_intra(
    const unsigned short* __restrict__ bcb,
    const unsigned short* __restrict__ xbc,
    const float* __restrict__ dtf, const float* __restrict__ lnAf,
    unsigned short* __restrict__ y1buf, unsigned short* __restrict__ SL,
    float* __restrict__ dtot) {
  const int bi = blockIdx.x;           // ((b*32+h)*16 + c), 1024 blocks
  const int c = bi & 15;
  const int h = (bi >> 4) & 31;
  const int b = bi >> 9;
  const int tid = threadIdx.x;
  const int w = tid >> 6, l = tid & 63, r = l & 15, quad = l >> 4;
  const size_t tok0 = (size_t)b * T_SEQ + c * 64;

  __shared__ __align__(16) unsigned short BCs[64 * 264];  // [t][B0..127|C128..255]+pad
  __shared__ __align__(16) unsigned short Xrow[64 * 72];  // [u][p]
  __shared__ __align__(16) unsigned short XTs[64 * 72];   // [p][u]
  __shared__ __align__(16) unsigned short BWT[128 * 72];  // [n][u] = ws[u]*B[u][n]
  __shared__ __align__(16) unsigned short Ms[64 * 72];    // [t][u]
  __shared__ float cumL[64], dtL[64], wsL[64];

#pragma unroll
  for (int i = 0; i < 8; ++i) {
    int idx = tid + i * 256;
    int row = idx >> 5, col = (idx & 31) * 8;
    uint4 v = *(const uint4*)(bcb + (tok0 + row) * 256 + col);
    *(uint4*)(BCs + row * 264 + col) = v;
  }
  // x tile: rows = tokens (coalesced 128B from xbc), cols = p
#pragma unroll
  for (int i = 0; i < 2; ++i) {
    int idx = tid + i * 256;
    int u = idx >> 3, pc = (idx & 7) * 8;
    uint4 v = *(const uint4*)(xbc + (tok0 + u) * CONVCH + h * HEADDIM + pc);
    *(uint4*)(Xrow + u * 72 + pc) = v;
  }
  if (tid < 64) {
    float dt = dtf[(tok0 + tid) * NHEADS + h];
    float v = lnAf[(tok0 + tid) * NHEADS + h];
    dtL[tid] = dt;
#pragma unroll
    for (int off = 1; off < 64; off <<= 1) {
      float u = __shfl_up(v, off, 64);
      if (tid >= off) v += u;
    }
    cumL[tid] = v;
    float tot = __shfl(v, 63, 64);   // scan total, in-wave broadcast
    wsL[tid] = dt * expf(tot - v);   // ws[u] = dt[u]*exp(cum63-cum[u]), once
    if (tid == 63) dtot[bi] = expf(tot);
  }
  __syncthreads();

  // in-LDS transpose: XTs[p][u] = x
#pragma unroll
  for (int i = 0; i < 2; ++i) {
    int idx = tid + i * 256;
    int p = idx >> 3, ug = (idx & 7) * 8;
    unsigned short tA[8];
#pragma unroll
    for (int j = 0; j < 8; ++j) tA[j] = Xrow[(ug + j) * 72 + p];
    *(uint4*)(XTs + p * 72 + ug) = *(uint4*)tA;
  }

  // cooperative B-transpose with ws fold: BWT[n][u] = ws[u]*B[u][n]
  {
    const int n = tid >> 1;
    const int ug = (tid & 1) * 32;
    unsigned short eb[32];
#pragma unroll
    for (int j = 0; j < 32; ++j)
      eb[j] = f2b(b2f(BCs[(ug + j) * 264 + n]) * wsL[ug + j]);
#pragma unroll
    for (int qq = 0; qq < 4; ++qq)
      *(uint4*)(BWT + n * 72 + ug + qq * 8) = *(uint4*)(eb + qq * 8);
  }

  // GEMM1: G = C·B^T  (64x64, K=128)
  f32x4 g[4];
#pragma unroll
  for (int nt = 0; nt < 4; ++nt) g[nt] = f32x4{0.f, 0.f, 0.f, 0.f};
#pragma unroll
  for (int kk = 0; kk < 4; ++kk) {
    bf16x8 afr = *(const bf16x8*)(BCs + (w * 16 + r) * 264 + 128 + kk * 32 + quad * 8);
#pragma unroll
    for (int nt = 0; nt < 4; ++nt) {
      bf16x8 bfr = *(const bf16x8*)(BCs + (nt * 16 + r) * 264 + kk * 32 + quad * 8);
      g[nt] = __builtin_amdgcn_mfma_f32_16x16x32_bf16(afr, bfr, g[nt], 0, 0, 0);
    }
  }
#pragma unroll
  for (int nt = 0; nt < 4; ++nt) {
#pragma unroll
    for (int i = 0; i < 4; ++i) {
      int t_ = w * 16 + quad * 4 + i;
      int u_ = nt * 16 + r;
      float wv = (u_ <= t_) ? expf(cumL[t_] - cumL[u_]) * dtL[u_] : 0.f;
      Ms[t_ * 72 + u_] = f2b(g[nt][i] * wv);
    }
  }
  __syncthreads();   // fences Ms, XTs, BWT writes -> GEMM2/GEMM3 reads

  // GEMM2: Y1 = M·X  (64t x 64p, K=64u)
  f32x4 y1[4];
#pragma unroll
  for (int nt = 0; nt < 4; ++nt) y1[nt] = f32x4{0.f, 0.f, 0.f, 0.f};
#pragma unroll
  for (int kk = 0; kk < 2; ++kk) {
    bf16x8 afr = *(const bf16x8*)(Ms + (w * 16 + r) * 72 + kk * 32 + quad * 8);
#pragma unroll
    for (int nt = 0; nt < 4; ++nt) {
      bf16x8 bfr = *(const bf16x8*)(XTs + (nt * 16 + r) * 72 + kk * 32 + quad * 8);
      y1[nt] = __builtin_amdgcn_mfma_f32_16x16x32_bf16(afr, bfr, y1[nt], 0, 0, 0);
    }
  }
#pragma unroll
  for (int nt = 0; nt < 4; ++nt)
#pragma unroll
    for (int i = 0; i < 4; ++i) {
      int t_ = w * 16 + quad * 4 + i, p_ = nt * 16 + r;
      y1buf[((size_t)bi * 64 + t_) * 64 + p_] = f2b(y1[nt][i]);
    }

  // GEMM3: Slocal[p][n] = sum_u XTs[p][u] * BWT[n][u]  (64p x 128n, K=64u)
  f32x4 sl[8];
#pragma unroll
  for (int nt = 0; nt < 8; ++nt) sl[nt] = f32x4{0.f, 0.f, 0.f, 0.f};
#pragma unroll
  for (int kk = 0; kk < 2; ++kk) {
    bf16x8 afr = *(const bf16x8*)(XTs + (w * 16 + r) * 72 + kk * 32 + quad * 8);
#pragma unroll
    for (int nt = 0; nt < 8; ++nt) {
      bf16x8 bfr = *(const bf16x8*)(BWT + (nt * 16 + r) * 72 + kk * 32 + quad * 8);
      sl[nt] = __builtin_amdgcn_mfma_f32_16x16x32_bf16(afr, bfr, sl[nt], 0, 0, 0);
    }
  }
#pragma unroll
  for (int nt = 0; nt < 8; ++nt)
#pragma unroll
    for (int i = 0; i < 4; ++i) {
      int p_ = w * 16 + quad * 4 + i, n_ = nt * 16 + r;
      SL[((size_t)bi * 64 + p_) * 128 + n_] = f2b(sl[nt][i]);
    }
}

// ---------------- SSD pass 2: chunk-state recurrence (in-place Slocal -> Spre) --------
__global__ void ssd_state(unsigned short* __restrict__ SL,
                          const float* __restrict__ dtot) {
  int gidx = blockIdx.x * 256 + threadIdx.x;   // 131072 = 64bh * 64p * 32(n/4)
  int n4 = (gidx & 31) * 4;
  int p = (gidx >> 5) & 63;
  int bh = gidx >> 11;
  float sx = 0.f, sy = 0.f, sz = 0.f, sw = 0.f;
  for (int c = 0; c < NCHUNK; ++c) {
    size_t off = ((size_t)(bh * 16 + c) * 64 + p) * 128 + n4;
    uint2 lv = *(uint2*)(SL + off);
    float d = dtot[bh * 16 + c];
    uint2 sv;
    sv.x = (unsigned)f2b(sx) | ((unsigned)f2b(sy) << 16);
    sv.y = (unsigned)f2b(sz) | ((unsigned)f2b(sw) << 16);
    *(uint2*)(SL + off) = sv;           // state BEFORE chunk c
    sx = d * sx + b2f(lv.x & 0xffff);
    sy = d * sy + b2f(lv.x >> 16);
    sz = d * sz + b2f(lv.y & 0xffff);
    sw = d * sw + b2f(lv.y >> 16);
  }
}

// ---------------- SSD pass 3: inter-chunk + combine + gate ----------------
// r18: accumulates per-token sum-of-squares of the gated f32 output into
// ssq[tok] (4-lane shfl reduce + 1 atomicAdd per token per block) for the
// fused RMSNorm in gemm<1>'s epilogue.
__global__ __launch_bounds__(256) void ssd_inter(
    const unsigned short* __restrict__ bcb,
    const unsigned short* __restrict__ SL,       // holds Spre now
    const unsigned short* __restrict__ y1buf,
    const unsigned short* __restrict__ xbc,
    const unsigned short* __restrict__ zx,
    const float* __restrict__ lnAf,
    const float* __restrict__ Dw,
    unsigned short* __restrict__ yg,
    float* __restrict__ ssq) {
  const int bi = blockIdx.x;
  const int c = bi & 15, h = (bi >> 4) & 31, b = bi >> 9;
  const int tid = threadIdx.x;
  const int w = tid >> 6, l = tid & 63, r = l & 15, quad = l >> 4;
  const size_t tok0 = (size_t)b * T_SEQ + c * 64;

  __shared__ __align__(16) unsigned short Cs[64 * 136];
  __shared__ __align__(16) unsigned short Sp[64 * 136];
  __shared__ __align__(16) float Yf[64 * 68];
  __shared__ float cumL[64];

#pragma unroll
  for (int i = 0; i < 4; ++i) {
    int idx = tid + i * 256;
    int row = idx >> 4, col = (idx & 15) * 8;
    uint4 v = *(const uint4*)(bcb + (tok0 + row) * 256 + 128 + col);
    *(uint4*)(Cs + row * 136 + col) = v;
    uint4 s = *(const uint4*)(SL + ((size_t)bi * 64 + row) * 128 + col);
    *(uint4*)(Sp + row * 136 + col) = s;
  }
  if (tid < 64) {
    float v = lnAf[(tok0 + tid) * NHEADS + h];
#pragma unroll
    for (int off = 1; off < 64; off <<= 1) {
      float u = __shfl_up(v, off, 64);
      if (tid >= off) v += u;
    }
    cumL[tid] = v;
  }
  __syncthreads();

  // Yi[t][p] = sum_n C[t][n]*Spre[p][n]  (K=128)
  f32x4 yi[4];
#pragma unroll
  for (int nt = 0; nt < 4; ++nt) yi[nt] = f32x4{0.f, 0.f, 0.f, 0.f};
#pragma unroll
  for (int kk = 0; kk < 4; ++kk) {
    bf16x8 afr = *(const bf16x8*)(Cs + (w * 16 + r) * 136 + kk * 32 + quad * 8);
#pragma unroll
    for (int nt = 0; nt < 4; ++nt) {
      bf16x8 bfr = *(const bf16x8*)(Sp + (nt * 16 + r) * 136 + kk * 32 + quad * 8);
      yi[nt] = __builtin_amdgcn_mfma_f32_16x16x32_bf16(afr, bfr, yi[nt], 0, 0, 0);
    }
  }
#pragma unroll
  for (int nt = 0; nt < 4; ++nt)
#pragma unroll
    for (int i = 0; i < 4; ++i) {
      int t_ = w * 16 + quad * 4 + i, p_ = nt * 16 + r;
      float y1 = b2f(y1buf[((size_t)bi * 64 + t_) * 64 + p_]);
      Yf[t_ * 68 + p_] = y1 + expf(cumL[t_]) * yi[nt][i];
    }
  __syncthreads();

  // combine: y = Yf + D*x, gate with silu(z), write yg + accumulate ssq
  const float Dh = Dw[h];
  const int t_ = tid >> 2, pg = (tid & 3) * 16;
  const size_t tok = tok0 + t_;
  union { uint4 q[2]; unsigned short u[16]; } xv, zv, ov;
  xv.q[0] = *(const uint4*)(xbc + tok * CONVCH + h * 64 + pg);
  xv.q[1] = *(const uint4*)(xbc + tok * CONVCH + h * 64 + pg + 8);
  zv.q[0] = *(const uint4*)(zx + tok * DINPROJ + h * 64 + pg);
  zv.q[1] = *(const uint4*)(zx + tok * DINPROJ + h * 64 + pg + 8);
  float ssf = 0.f;
#pragma unroll
  for (int j = 0; j < 16; ++j) {
    float y = Yf[t_ * 68 + pg + j] + Dh * b2f(xv.u[j]);
    float zf = b2f(zv.u[j]);
    float yg_f = y * (zf / (1.f + expf(-zf)));
    ov.u[j] = f2b(yg_f);
    ssf += yg_f * yg_f;
  }
  *(uint4*)(yg + tok * DINNER + h * 64 + pg) = ov.q[0];
  *(uint4*)(yg + tok * DINNER + h * 64 + pg + 8) = ov.q[1];
  // reduce the 4 lanes of this token, one atomic per token per block
  ssf += __shfl_xor(ssf, 1, 64);
  ssf += __shfl_xor(ssf, 2, 64);
  if ((tid & 3) == 0) atomicAdd(&ssq[tok], ssf);
}

// ---------------- final RMSNorm over 1024 ----------------
__global__ void rmsfinal_k(const float* __restrict__ hf,
                           const float* __restrict__ w,
                           unsigned short* __restrict__ out) {
  int t = blockIdx.x;
  int base = threadIdx.x * 4;
  float4 v = *(const float4*)(hf + (size_t)t * DIM + base);
  float ss = v.x * v.x + v.y * v.y + v.z * v.z + v.w * v.w;
#pragma unroll
  for (int o = 32; o > 0; o >>= 1) ss += __shfl_xor(ss, o, 64);
  __shared__ float red[4];
  if ((threadIdx.x & 63) == 0) red[threadIdx.x >> 6] = ss;
  __syncthreads();
  ss = red[0] + red[1] + red[2] + red[3];
  float scale = rsqrtf(ss * (1.f / DIM) + EPS_F);
  out[(size_t)t * DIM + base + 0] = f2b(v.x * scale * w[base + 0]);
  out[(size_t)t * DIM + base + 1] = f2b(v.y * scale * w[base + 1]);
  out[(size_t)t * DIM + base + 2] = f2b(v.z * scale * w[base + 2]);
  out[(size_t)t * DIM + base + 3] = f2b(v.w * scale * w[base + 3]);
}

extern "C" void kernel_launch(void* const* d_in, const int* in_sizes, int n_in,
                              void* d_out, int out_size, void* d_ws, size_t ws_size,
                              hipStream_t stream) {
  const int*   x    = (const int*)d_in[0];
  const float* emb  = (const float*)d_in[1];
  const float* Wp   = (const float*)d_in[2];
  const float* cw   = (const float*)d_in[3];
  const float* cb   = (const float*)d_in[4];
  const float* dtb  = (const float*)d_in[5];
  const float* alog = (const float*)d_in[6];
  const float* Dw   = (const float*)d_in[7];
  const float* gw   = (const float*)d_in[8];
  const float* Wo   = (const float*)d_in[9];
  const float* fnw  = (const float*)d_in[10];

  char* w = (char*)d_ws;
  auto alloc = [&](size_t bytes) {
    char* p = w; w += (bytes + 255) & ~(size_t)255; return p;
  };
  float* h_f32          = (float*)alloc((size_t)BT * DIM * 4);
  unsigned short* hb    = (unsigned short*)alloc((size_t)BT * DIM * 2);
  unsigned short* zx    = (unsigned short*)alloc((size_t)BT * DINPROJ * 2);
  float* dtraw          = (float*)alloc((size_t)BT * NHEADS * 4);
  float* dtf            = (float*)alloc((size_t)BT * NHEADS * 4);
  float* lnAf           = (float*)alloc((size_t)BT * NHEADS * 4);
  unsigned short* xbc   = (unsigned short*)alloc((size_t)BT * CONVCH * 2);
  unsigned short* bcb   = (unsigned short*)alloc((size_t)BT * 256 * 2);
  unsigned short* SL    = (unsigned short*)alloc((size_t)1024 * 64 * 128 * 2);
  unsigned short* y1buf = (unsigned short*)alloc((size_t)1024 * 64 * 64 * 2);
  float* dtot           = (float*)alloc((size_t)1024 * 4);
  unsigned short* yg    = (unsigned short*)alloc((size_t)BT * DINNER * 2);
  float* ssq            = (float*)alloc((size_t)BT * 4);
  unsigned short* hn    = (unsigned short*)alloc((size_t)BT * DIM * 2);
  unsigned short* Wp_b  = (unsigned short*)alloc((size_t)2 * DINPROJ * DIM * 2);
  unsigned short* Wo_b  = (unsigned short*)alloc((size_t)2 * DIM * DINNER * 2);
  unsigned short* emb_b = (unsigned short*)alloc((size_t)256 * DIM * 2 + 256);

  // fused prologue: 3x weight cvt (gw folded into Wo) + embed in ONE launch
  prologue_k<<<PRO_BLK, 256, 0, stream>>>(Wp, Wo, emb, gw, Wp_b, Wo_b, emb_b, x, h_f32, hb);

  for (int l = 0; l < 2; ++l) {
    const unsigned short* Wpl = Wp_b + (size_t)l * DINPROJ * DIM;
    const unsigned short* Wol = Wo_b + (size_t)l * DIM * DINNER;
    const float* cwl   = cw + (size_t)l * CONVCH * 4;
    const float* cbl   = cb + (size_t)l * CONVCH;
    const float* dtbl  = dtb + l * NHEADS;
    const float* alogl = alog + l * NHEADS;
    const float* Dwl   = Dw + l * NHEADS;

    gemm_bt<0, 128, 128><<<dim3(35, 16), 256, 0, stream>>>(hb, Wpl, BT, DINPROJ, DIM, zx, dtraw, nullptr, nullptr);
    conv_k<<<BT, 256, 0, stream>>>(zx, cwl, cbl, xbc, bcb, dtraw, dtbl, alogl, dtf, lnAf, ssq);
    ssd_intra<<<1024, 256, 0, stream>>>(bcb, xbc, dtf, lnAf, y1buf, SL, dtot);
    ssd_state<<<512, 256, 0, stream>>>(SL, dtot);
    ssd_inter<<<1024, 256, 0, stream>>>(bcb, SL, y1buf, xbc, zx, lnAf, Dwl, yg, ssq);
    gemm_bt<1, 64, 64><<<dim3(16, 32), 256, 0, stream>>>(yg, Wol, BT, DIM, DINNER, nullptr, h_f32, hb, ssq);
  }

  rmsfinal_k<<<BT, 256, 0, stream>>>(h_f32, fnw, hn);
  gemm_bt<2, 64, 64><<<dim3(4, 32), 256, 0, stream>>>(hn, emb_b, BT, 256, DIM,
                                                      nullptr, (float*)d_out, nullptr, nullptr);
}

// Round 21
// 356.180 us; speedup vs baseline: 1.0352x; 1.0260x over previous
//
#include <hip/hip_runtime.h>
#include <hip/hip_bf16.h>

#define BT 2048
#define T_SEQ 1024
#define DIM 1024
#define DINNER 2048
#define DSTATE 128
#define HEADDIM 64
#define NHEADS 32
#define CONVCH 2304
#define DINPROJ 4384
#define EPS_F 1e-5f
#define NCHUNK 16   // T_SEQ / 64

typedef __bf16 bf16x8 __attribute__((ext_vector_type(8)));
typedef float f32x4 __attribute__((ext_vector_type(4)));

__device__ __forceinline__ float b2f(unsigned short u) {
  union { unsigned int i; float f; } v; v.i = ((unsigned int)u) << 16; return v.f;
}
__device__ __forceinline__ unsigned short f2b(float f) {
  unsigned int x = __float_as_uint(f);
  return (unsigned short)((x + 0x7fffu + ((x >> 16) & 1u)) >> 16);
}

// async global->LDS DMA (gemm staging)
__device__ __forceinline__ void gload_lds16(const void* g, void* l) {
  __builtin_amdgcn_global_load_lds(
      (const __attribute__((address_space(1))) unsigned int*)g,
      (__attribute__((address_space(3))) unsigned int*)l, 16, 0, 0);
}

// ---------------- fused prologue: 3x fp32->bf16 weight cvt + embed ----------
// r17-validated (-3 launches). r18: gw (RMSNorm gamma) folded into Wo_b.
#define NWP_ELEM (2 * DINPROJ * DIM)     // 8,978,432
#define NWO_ELEM (2 * DIM * DINNER)      // 4,194,304
#define NEM_ELEM (256 * DIM)             // 262,144
#define NWP_BLK (NWP_ELEM / 4 / 256)     // 8768
#define NWO_BLK (NWO_ELEM / 4 / 256)     // 4096
#define NEM_BLK (NEM_ELEM / 4 / 256)     // 256
#define PRO_BLK (NWP_BLK + NWO_BLK + NEM_BLK + BT)   // 15168

__global__ void prologue_k(const float* __restrict__ Wp, const float* __restrict__ Wo,
                           const float* __restrict__ emb, const float* __restrict__ gw,
                           unsigned short* __restrict__ Wp_b,
                           unsigned short* __restrict__ Wo_b,
                           unsigned short* __restrict__ emb_b,
                           const int* __restrict__ x,
                           float* __restrict__ h, unsigned short* __restrict__ hb) {
  int bid = blockIdx.x;
  if (bid < NWP_BLK) {
    int i = (bid * 256 + threadIdx.x) * 4;
    float4 v = *(const float4*)(Wp + i);
    Wp_b[i + 0] = f2b(v.x); Wp_b[i + 1] = f2b(v.y);
    Wp_b[i + 2] = f2b(v.z); Wp_b[i + 3] = f2b(v.w);
  } else if (bid < NWP_BLK + NWO_BLK) {
    int i = ((bid - NWP_BLK) * 256 + threadIdx.x) * 4;
    int li = i / (DIM * DINNER);
    int kk = i & (DINNER - 1);          // i % DINNER (i multiple of 4, no wrap)
    float4 v = *(const float4*)(Wo + i);
    float4 g = *(const float4*)(gw + li * DINNER + kk);
    Wo_b[i + 0] = f2b(v.x * g.x); Wo_b[i + 1] = f2b(v.y * g.y);
    Wo_b[i + 2] = f2b(v.z * g.z); Wo_b[i + 3] = f2b(v.w * g.w);
  } else if (bid < NWP_BLK + NWO_BLK + NEM_BLK) {
    int i = ((bid - NWP_BLK - NWO_BLK) * 256 + threadIdx.x) * 4;
    float4 v = *(const float4*)(emb + i);
    emb_b[i + 0] = f2b(v.x); emb_b[i + 1] = f2b(v.y);
    emb_b[i + 2] = f2b(v.z); emb_b[i + 3] = f2b(v.w);
  } else {
    int t = bid - (NWP_BLK + NWO_BLK + NEM_BLK);
    int tok = x[t];
    int d = threadIdx.x;
#pragma unroll
    for (int j = 0; j < 4; ++j, d += 256) {
      float v = emb[(size_t)tok * DIM + d];
      h[(size_t)t * DIM + d] = v;
      hb[(size_t)t * DIM + d] = f2b(v);
    }
  }
}

// ---------------- GEMM: C[M,N] = A[M,K] * Bw[N,K]^T (bf16, fp32 acc) ----------------
// r9-validated 2-phase dbuf structure; T1 XCD column-major swizzle.
// r21: BK templated. gemm<0> stays BK=32 (r10 showed BK=64 at 128^2 costs
// residency: 64KB LDS caps 2 blocks/CU). gemm<1>/gemm<2> (64^2 tiles) use
// BK=64: LDS 32KB -> cap 5/CU while grid limits to <=2/CU anyway
// (residency-NEUTRAL), and the barrier-drain count halves (gemm<1>: 64->32
// drains over K=2048 -- its dominant stall). BK=64 needs the 16B-slot XOR
// swizzle (128B rows = 16-way conflict otherwise); mechanics verified
// correct + conflict-free in r10 (passed, SQ_LDS_BANK_CONFLICT=0).
// MODE==1 applies the fused RMSNorm row-scale (r18).
template <int MODE, int TM, int TN, int BK>
__global__ __launch_bounds__(256) void gemm_bt(
    const unsigned short* __restrict__ A,
    const unsigned short* __restrict__ Bw,
    int M, int N, int K,
    unsigned short* __restrict__ Cout,
    float* __restrict__ aux,
    unsigned short* __restrict__ aux2,
    const float* __restrict__ ssq) {
  constexpr int FM = TM / 32, FN = TN / 32;
  constexpr int RPC = 2048 / BK;           // rows per 4KB staging chunk
  constexpr int CA = TM / RPC, CB = TN / RPC;
  constexpr int KK = BK / 32;              // mfma k-slices per K-step
  constexpr int SPR = BK / 8;              // 16B slots per row
  constexpr int TPR = BK / 8;              // staging threads per row
  constexpr int HA = TM * BK, HB = TN * BK;   // elements per buffer
  __shared__ __align__(16) unsigned short As[2 * HA];
  __shared__ __align__(16) unsigned short Bs[2 * HB];
  const int tid = threadIdx.x;
  const int lane = tid & 63;
  const int wave = tid >> 6;

  // bijective XCD remap (m204): column-major chunks per XCD for B-panel L2 reuse.
  const int gx = gridDim.x, gy = gridDim.y;
  const int nwg = gx * gy;
  const int orig = (int)(blockIdx.y * gx + blockIdx.x);
  const int q = nwg >> 3, rr = nwg & 7;
  const int xcd = orig & 7, idx = orig >> 3;
  const int swz = (xcd < rr ? xcd * (q + 1) : rr * (q + 1) + (xcd - rr) * q) + idx;
  const int bxs = swz / gy;          // n-tile (column-major walk)
  const int bys = swz - bxs * gy;    // m-tile
  const int m0 = bys * TM;
  const int n0 = bxs * TN;

  const int wm = (wave >> 1) * (TM / 2);
  const int wn = (wave & 1) * (TN / 2);
  const int quad = lane >> 4;
  const int r = lane & 15;
  const int sa = (BK == 64) ? (r & 7) : 0;   // read-side swizzle key (row&7==r&7)

  f32x4 acc[FM][FN];
#pragma unroll
  for (int i = 0; i < FM; ++i)
#pragma unroll
    for (int j = 0; j < FN; ++j) acc[i][j] = f32x4{0.f, 0.f, 0.f, 0.f};

  // staging: thread tid fills row (tid/TPR), slot (tid%TPR) of each chunk.
  // BK=64: global column pre-swizzled so LDS slot s holds global slot
  // s^(row&7) (involution; read applies the same XOR). LDS dest stays linear
  // (rule #21: gload_lds writes base+lane*16).
  const int rowt = tid / TPR;
  int colb = tid % TPR;
  if (BK == 64) colb ^= (rowt & 7);
  const int colt = colb * 8;
  const unsigned short* aG[CA];
  unsigned short* aD[CA];
  const unsigned short* bG[CB];
  unsigned short* bD[CB];
#pragma unroll
  for (int j = 0; j < CA; ++j) {
    aG[j] = A + (size_t)(m0 + j * RPC + rowt) * K + colt;
    aD[j] = As + wave * 512 + j * 2048;
  }
#pragma unroll
  for (int j = 0; j < CB; ++j) {
    int rb = n0 + j * RPC + rowt; if (rb >= N) rb = N - 1;
    bG[j] = Bw + (size_t)rb * K + colt;
    bD[j] = Bs + wave * 512 + j * 2048;
  }

  // prologue: stage K-tile 0 into buffer 0
#pragma unroll
  for (int j = 0; j < CA; ++j) gload_lds16(aG[j], aD[j]);
#pragma unroll
  for (int j = 0; j < CB; ++j) gload_lds16(bG[j], bD[j]);
  __syncthreads();   // drains vmcnt(0) -> buffer 0 visible

  int cur = 0;
  for (int k0 = 0; k0 < K; k0 += BK) {
    const int nxt = cur ^ 1;
    // issue prefetch of next K-tile into the other buffer (in flight during MFMA)
    if (k0 + BK < K) {
#pragma unroll
      for (int j = 0; j < CA; ++j) gload_lds16(aG[j] + k0 + BK, aD[j] + nxt * HA);
#pragma unroll
      for (int j = 0; j < CB; ++j) gload_lds16(bG[j] + k0 + BK, bD[j] + nxt * HB);
    }
    const bf16x8* ap = (const bf16x8*)(As + cur * HA);
    const bf16x8* bp = (const bf16x8*)(Bs + cur * HB);
    bf16x8 af[KK][FM], bfr[KK][FN];
#pragma unroll
    for (int kk = 0; kk < KK; ++kk) {
      const int slot = (BK == 64) ? ((kk * 4 + quad) ^ sa) : quad;
#pragma unroll
      for (int mt = 0; mt < FM; ++mt)
        af[kk][mt] = ap[(wm + mt * 16 + r) * SPR + slot];
#pragma unroll
      for (int nt = 0; nt < FN; ++nt)
        bfr[kk][nt] = bp[(wn + nt * 16 + r) * SPR + slot];
    }
#pragma unroll
    for (int kk = 0; kk < KK; ++kk)
#pragma unroll
      for (int mt = 0; mt < FM; ++mt)
#pragma unroll
        for (int nt = 0; nt < FN; ++nt)
          acc[mt][nt] = __builtin_amdgcn_mfma_f32_16x16x32_bf16(af[kk][mt], bfr[kk][nt], acc[mt][nt], 0, 0, 0);
    __syncthreads();  // drains prefetch (hidden under MFMA) + read-done fence
    cur = nxt;
  }

#pragma unroll
  for (int mt = 0; mt < FM; ++mt) {
#pragma unroll
    for (int nt = 0; nt < FN; ++nt) {
#pragma unroll
      for (int i = 0; i < 4; ++i) {
        int gm = m0 + wm + mt * 16 + quad * 4 + i;
        int gn = n0 + wn + nt * 16 + r;
        if (gn < N) {
          float v = acc[mt][nt][i];
          if (MODE == 0) {
            Cout[(size_t)gm * N + gn] = f2b(v);
            if (gn >= DINNER + CONVCH)
              aux[(size_t)gm * NHEADS + (gn - (DINNER + CONVCH))] = v;
          } else if (MODE == 1) {
            float scl = rsqrtf(ssq[gm] * (1.f / DINNER) + EPS_F);
            size_t o = (size_t)gm * N + gn;
            float hnv = aux[o] + v * scl;
            aux[o] = hnv;
            aux2[o] = f2b(hnv);
          } else {
            aux[(size_t)gm * N + gn] = v;
          }
        }
      }
    }
  }
}

// ---------------- causal conv (K=4) + silu, with fused dt/lnA ----------------
// r9 scalar form (measured best). r18: thread 0 zeroes ssq[t].
__global__ void conv_k(const unsigned short* __restrict__ zx,
                       const float* __restrict__ cw,
                       const float* __restrict__ cb,
                       unsigned short* __restrict__ xbc,
                       unsigned short* __restrict__ bcb,
                       const float* __restrict__ dtraw,
                       const float* __restrict__ dtb,
                       const float* __restrict__ alog,
                       float* __restrict__ dtf,
                       float* __restrict__ lnAf,
                       float* __restrict__ ssq) {
  int t = blockIdx.x;
  int tt = t & (T_SEQ - 1);
  if (threadIdx.x == 0) ssq[t] = 0.f;
  if (threadIdx.x < NHEADS) {
    int h = threadIdx.x;
    float xx = dtraw[t * NHEADS + h] + dtb[h];
    float sp = (xx > 20.f) ? xx : log1pf(expf(xx));
    dtf[t * NHEADS + h] = sp;
    lnAf[t * NHEADS + h] = -sp * expf(alog[h]);
  }
  for (int c = threadIdx.x; c < CONVCH; c += 256) {
    float acc = cb[c];
#pragma unroll
    for (int k = 0; k < 4; ++k) {
      int tp = tt - 3 + k;
      if (tp >= 0)
        acc += b2f(zx[(size_t)(t - 3 + k) * DINPROJ + DINNER + c]) * cw[c * 4 + k];
    }
    float s = acc / (1.f + expf(-acc));
    unsigned short sb = f2b(s);
    xbc[(size_t)t * CONVCH + c] = sb;
    if (c >= DINNER) bcb[(size_t)t * 256 + (c - DINNER)] = sb;
  }
}

// ---------------- SSD pass 1: intra-chunk (per (b,h,chunk)) ----------------
// r8 (validated): wsL precompute + BWT cooperative transpose.
__global__ __launch_bounds__(256) void ssd_intra(
    const unsigned short* __restrict__ bcb,
    const unsigned short* __restrict__ xbc,
    const float* __restrict__ dtf, const float* __restrict__ lnAf,
    unsigned short* __restrict__ y1buf, unsigned short* __restrict__ SL,
    float* __restrict__ dtot) {
  const int bi = blockIdx.x;           // ((b*32+h)*16 + c), 1024 blocks
  const int c = bi & 15;
  const int h = (bi >> 4) & 31;
  const int b = bi >> 9;
  const int tid = threadIdx.x;
  const int w = tid >> 6, l = tid & 63, r = l & 15, quad = l >> 4;
  const size_t tok0 = (size_t)b * T_SEQ + c * 64;

  __shared__ __align__(16) unsigned short BCs[64 * 264];  // [t][B0..127|C128..255]+pad
  __shared__ __align__(16) unsigned short Xrow[64 * 72];  // [u][p]
  __shared__ __align__(16) unsigned short XTs[64 * 72];   // [p][u]
  __shared__ __align__(16) unsigned short BWT[128 * 72];  // [n][u] = ws[u]*B[u][n]
  __shared__ __align__(16) unsigned short Ms[64 * 72];    // [t][u]
  __shared__ float cumL[64], dtL[64], wsL[64];

#pragma unroll
  for (int i = 0; i < 8; ++i) {
    int idx = tid + i * 256;
    int row = idx >> 5, col = (idx & 31) * 8;
    uint4 v = *(const uint4*)(bcb + (tok0 + row) * 256 + col);
    *(uint4*)(BCs + row * 264 + col) = v;
  }
  // x tile: rows = tokens (coalesced 128B from xbc), cols = p
#pragma unroll
  for (int i = 0; i < 2; ++i) {
    int idx = tid + i * 256;
    int u = idx >> 3, pc = (idx & 7) * 8;
    uint4 v = *(const uint4*)(xbc + (tok0 + u) * CONVCH + h * HEADDIM + pc);
    *(uint4*)(Xrow + u * 72 + pc) = v;
  }
  if (tid < 64) {
    float dt = dtf[(tok0 + tid) * NHEADS + h];
    float v = lnAf[(tok0 + tid) * NHEADS + h];
    dtL[tid] = dt;
#pragma unroll
    for (int off = 1; off < 64; off <<= 1) {
      float u = __shfl_up(v, off, 64);
      if (tid >= off) v += u;
    }
    cumL[tid] = v;
    float tot = __shfl(v, 63, 64);   // scan total, in-wave broadcast
    wsL[tid] = dt * expf(tot - v);   // ws[u] = dt[u]*exp(cum63-cum[u]), once
    if (tid == 63) dtot[bi] = expf(tot);
  }
  __syncthreads();

  // in-LDS transpose: XTs[p][u] = x
#pragma unroll
  for (int i = 0; i < 2; ++i) {
    int idx = tid + i * 256;
    int p = idx >> 3, ug = (idx & 7) * 8;
    unsigned short tA[8];
#pragma unroll
    for (int j = 0; j < 8; ++j) tA[j] = Xrow[(ug + j) * 72 + p];
    *(uint4*)(XTs + p * 72 + ug) = *(uint4*)tA;
  }

  // cooperative B-transpose with ws fold: BWT[n][u] = ws[u]*B[u][n]
  {
    const int n = tid >> 1;
    const int ug = (tid & 1) * 32;
    unsigned short eb[32];
#pragma unroll
    for (int j = 0; j < 32; ++j)
      eb[j] = f2b(b2f(BCs[(ug + j) * 264 + n]) * wsL[ug + j]);
#pragma unroll
    for (int qq = 0; qq < 4; ++qq)
      *(uint4*)(BWT + n * 72 + ug + qq * 8) = *(uint4*)(eb + qq * 8);
  }

  // GEMM1: G = C·B^T  (64x64, K=128)
  f32x4 g[4];
#pragma unroll
  for (int nt = 0; nt < 4; ++nt) g[nt] = f32x4{0.f, 0.f, 0.f, 0.f};
#pragma unroll
  for (int kk = 0; kk < 4; ++kk) {
    bf16x8 afr = *(const bf16x8*)(BCs + (w * 16 + r) * 264 + 128 + kk * 32 + quad * 8);
#pragma unroll
    for (int nt = 0; nt < 4; ++nt) {
      bf16x8 bfr = *(const bf16x8*)(BCs + (nt * 16 + r) * 264 + kk * 32 + quad * 8);
      g[nt] = __builtin_amdgcn_mfma_f32_16x16x32_bf16(afr, bfr, g[nt], 0, 0, 0);
    }
  }
#pragma unroll
  for (int nt = 0; nt < 4; ++nt) {
#pragma unroll
    for (int i = 0; i < 4; ++i) {
      int t_ = w * 16 + quad * 4 + i;
      int u_ = nt * 16 + r;
      float wv = (u_ <= t_) ? expf(cumL[t_] - cumL[u_]) * dtL[u_] : 0.f;
      Ms[t_ * 72 + u_] = f2b(g[nt][i] * wv);
    }
  }
  __syncthreads();   // fences Ms, XTs, BWT writes -> GEMM2/GEMM3 reads

  // GEMM2: Y1 = M·X  (64t x 64p, K=64u)
  f32x4 y1[4];
#pragma unroll
  for (int nt = 0; nt < 4; ++nt) y1[nt] = f32x4{0.f, 0.f, 0.f, 0.f};
#pragma unroll
  for (int kk = 0; kk < 2; ++kk) {
    bf16x8 afr = *(const bf16x8*)(Ms + (w * 16 + r) * 72 + kk * 32 + quad * 8);
#pragma unroll
    for (int nt = 0; nt < 4; ++nt) {
      bf16x8 bfr = *(const bf16x8*)(XTs + (nt * 16 + r) * 72 + kk * 32 + quad * 8);
      y1[nt] = __builtin_amdgcn_mfma_f32_16x16x32_bf16(afr, bfr, y1[nt], 0, 0, 0);
    }
  }
#pragma unroll
  for (int nt = 0; nt < 4; ++nt)
#pragma unroll
    for (int i = 0; i < 4; ++i) {
      int t_ = w * 16 + quad * 4 + i, p_ = nt * 16 + r;
      y1buf[((size_t)bi * 64 + t_) * 64 + p_] = f2b(y1[nt][i]);
    }

  // GEMM3: Slocal[p][n] = sum_u XTs[p][u] * BWT[n][u]  (64p x 128n, K=64u)
  f32x4 sl[8];
#pragma unroll
  for (int nt = 0; nt < 8; ++nt) sl[nt] = f32x4{0.f, 0.f, 0.f, 0.f};
#pragma unroll
  for (int kk = 0; kk < 2; ++kk) {
    bf16x8 afr = *(const bf16x8*)(XTs + (w * 16 + r) * 72 + kk * 32 + quad * 8);
#pragma unroll
    for (int nt = 0; nt < 8; ++nt) {
      bf16x8 bfr = *(const bf16x8*)(BWT + (nt * 16 + r) * 72 + kk * 32 + quad * 8);
      sl[nt] = __builtin_amdgcn_mfma_f32_16x16x32_bf16(afr, bfr, sl[nt], 0, 0, 0);
    }
  }
#pragma unroll
  for (int nt = 0; nt < 8; ++nt)
#pragma unroll
    for (int i = 0; i < 4; ++i) {
      int p_ = w * 16 + quad * 4 + i, n_ = nt * 16 + r;
      SL[((size_t)bi * 64 + p_) * 128 + n_] = f2b(sl[nt][i]);
    }
}

// ---------------- SSD pass 2: chunk-state recurrence (in-place Slocal -> Spre) --------
__global__ void ssd_state(unsigned short* __restrict__ SL,
                          const float* __restrict__ dtot) {
  int gidx = blockIdx.x * 256 + threadIdx.x;   // 131072 = 64bh * 64p * 32(n/4)
  int n4 = (gidx & 31) * 4;
  int p = (gidx >> 5) & 63;
  int bh = gidx >> 11;
  float sx = 0.f, sy = 0.f, sz = 0.f, sw = 0.f;
  for (int c = 0; c < NCHUNK; ++c) {
    size_t off = ((size_t)(bh * 16 + c) * 64 + p) * 128 + n4;
    uint2 lv = *(uint2*)(SL + off);
    float d = dtot[bh * 16 + c];
    uint2 sv;
    sv.x = (unsigned)f2b(sx) | ((unsigned)f2b(sy) << 16);
    sv.y = (unsigned)f2b(sz) | ((unsigned)f2b(sw) << 16);
    *(uint2*)(SL + off) = sv;           // state BEFORE chunk c
    sx = d * sx + b2f(lv.x & 0xffff);
    sy = d * sy + b2f(lv.x >> 16);
    sz = d * sz + b2f(lv.y & 0xffff);
    sw = d * sw + b2f(lv.y >> 16);
  }
}

// ---------------- SSD pass 3: inter-chunk + combine + gate ----------------
// r18: accumulates per-token sum-of-squares of the gated f32 output into
// ssq[tok] (2 shfl + 1 atomicAdd per token per block) for the fused RMSNorm
// in gemm<1>'s epilogue.
__global__ __launch_bounds__(256) void ssd_inter(
    const unsigned short* __restrict__ bcb,
    const unsigned short* __restrict__ SL,       // holds Spre now
    const unsigned short* __restrict__ y1buf,
    const unsigned short* __restrict__ xbc,
    const unsigned short* __restrict__ zx,
    const float* __restrict__ lnAf,
    const float* __restrict__ Dw,
    unsigned short* __restrict__ yg,
    float* __restrict__ ssq) {
  const int bi = blockIdx.x;
  const int c = bi & 15, h = (bi >> 4) & 31, b = bi >> 9;
  const int tid = threadIdx.x;
  const int w = tid >> 6, l = tid & 63, r = l & 15, quad = l >> 4;
  const size_t tok0 = (size_t)b * T_SEQ + c * 64;

  __shared__ __align__(16) unsigned short Cs[64 * 136];
  __shared__ __align__(16) unsigned short Sp[64 * 136];
  __shared__ __align__(16) float Yf[64 * 68];
  __shared__ float cumL[64];

#pragma unroll
  for (int i = 0; i < 4; ++i) {
    int idx = tid + i * 256;
    int row = idx >> 4, col = (idx & 15) * 8;
    uint4 v = *(const uint4*)(bcb + (tok0 + row) * 256 + 128 + col);
    *(uint4*)(Cs + row * 136 + col) = v;
    uint4 s = *(const uint4*)(SL + ((size_t)bi * 64 + row) * 128 + col);
    *(uint4*)(Sp + row * 136 + col) = s;
  }
  if (tid < 64) {
    float v = lnAf[(tok0 + tid) * NHEADS + h];
#pragma unroll
    for (int off = 1; off < 64; off <<= 1) {
      float u = __shfl_up(v, off, 64);
      if (tid >= off) v += u;
    }
    cumL[tid] = v;
  }
  __syncthreads();

  // Yi[t][p] = sum_n C[t][n]*Spre[p][n]  (K=128)
  f32x4 yi[4];
#pragma unroll
  for (int nt = 0; nt < 4; ++nt) yi[nt] = f32x4{0.f, 0.f, 0.f, 0.f};
#pragma unroll
  for (int kk = 0; kk < 4; ++kk) {
    bf16x8 afr = *(const bf16x8*)(Cs + (w * 16 + r) * 136 + kk * 32 + quad * 8);
#pragma unroll
    for (int nt = 0; nt < 4; ++nt) {
      bf16x8 bfr = *(const bf16x8*)(Sp + (nt * 16 + r) * 136 + kk * 32 + quad * 8);
      yi[nt] = __builtin_amdgcn_mfma_f32_16x16x32_bf16(afr, bfr, yi[nt], 0, 0, 0);
    }
  }
#pragma unroll
  for (int nt = 0; nt < 4; ++nt)
#pragma unroll
    for (int i = 0; i < 4; ++i) {
      int t_ = w * 16 + quad * 4 + i, p_ = nt * 16 + r;
      float y1 = b2f(y1buf[((size_t)bi * 64 + t_) * 64 + p_]);
      Yf[t_ * 68 + p_] = y1 + expf(cumL[t_]) * yi[nt][i];
    }
  __syncthreads();

  // combine: y = Yf + D*x, gate with silu(z), write yg + accumulate ssq
  const float Dh = Dw[h];
  const int t_ = tid >> 2, pg = (tid & 3) * 16;
  const size_t tok = tok0 + t_;
  union { uint4 q[2]; unsigned short u[16]; } xv, zv, ov;
  xv.q[0] = *(const uint4*)(xbc + tok * CONVCH + h * 64 + pg);
  xv.q[1] = *(const uint4*)(xbc + tok * CONVCH + h * 64 + pg + 8);
  zv.q[0] = *(const uint4*)(zx + tok * DINPROJ + h * 64 + pg);
  zv.q[1] = *(const uint4*)(zx + tok * DINPROJ + h * 64 + pg + 8);
  float ssf = 0.f;
#pragma unroll
  for (int j = 0; j < 16; ++j) {
    float y = Yf[t_ * 68 + pg + j] + Dh * b2f(xv.u[j]);
    float zf = b2f(zv.u[j]);
    float yg_f = y * (zf / (1.f + expf(-zf)));
    ov.u[j] = f2b(yg_f);
    ssf += yg_f * yg_f;
  }
  *(uint4*)(yg + tok * DINNER + h * 64 + pg) = ov.q[0];
  *(uint4*)(yg + tok * DINNER + h * 64 + pg + 8) = ov.q[1];
  // reduce the 4 lanes of this token, one atomic per token per block
  ssf += __shfl_xor(ssf, 1, 64);
  ssf += __shfl_xor(ssf, 2, 64);
  if ((tid & 3) == 0) atomicAdd(&ssq[tok], ssf);
}

// ---------------- final RMSNorm over 1024 ----------------
__global__ void rmsfinal_k(const float* __restrict__ hf,
                           const float* __restrict__ w,
                           unsigned short* __restrict__ out) {
  int t = blockIdx.x;
  int base = threadIdx.x * 4;
  float4 v = *(const float4*)(hf + (size_t)t * DIM + base);
  float ss = v.x * v.x + v.y * v.y + v.z * v.z + v.w * v.w;
#pragma unroll
  for (int o = 32; o > 0; o >>= 1) ss += __shfl_xor(ss, o, 64);
  __shared__ float red[4];
  if ((threadIdx.x & 63) == 0) red[threadIdx.x >> 6] = ss;
  __syncthreads();
  ss = red[0] + red[1] + red[2] + red[3];
  float scale = rsqrtf(ss * (1.f / DIM) + EPS_F);
  out[(size_t)t * DIM + base + 0] = f2b(v.x * scale * w[base + 0]);
  out[(size_t)t * DIM + base + 1] = f2b(v.y * scale * w[base + 1]);
  out[(size_t)t * DIM + base + 2] = f2b(v.z * scale * w[base + 2]);
  out[(size_t)t * DIM + base + 3] = f2b(v.w * scale * w[base + 3]);
}

extern "C" void kernel_launch(void* const* d_in, const int* in_sizes, int n_in,
                              void* d_out, int out_size, void* d_ws, size_t ws_size,
                              hipStream_t stream) {
  const int*   x    = (const int*)d_in[0];
  const float* emb  = (const float*)d_in[1];
  const float* Wp   = (const float*)d_in[2];
  const float* cw   = (const float*)d_in[3];
  const float* cb   = (const float*)d_in[4];
  const float* dtb  = (const float*)d_in[5];
  const float* alog = (const float*)d_in[6];
  const float* Dw   = (const float*)d_in[7];
  const float* gw   = (const float*)d_in[8];
  const float* Wo   = (const float*)d_in[9];
  const float* fnw  = (const float*)d_in[10];

  char* w = (char*)d_ws;
  auto alloc = [&](size_t bytes) {
    char* p = w; w += (bytes + 255) & ~(size_t)255; return p;
  };
  float* h_f32          = (float*)alloc((size_t)BT * DIM * 4);
  unsigned short* hb    = (unsigned short*)alloc((size_t)BT * DIM * 2);
  unsigned short* zx    = (unsigned short*)alloc((size_t)BT * DINPROJ * 2);
  float* dtraw          = (float*)alloc((size_t)BT * NHEADS * 4);
  float* dtf            = (float*)alloc((size_t)BT * NHEADS * 4);
  float* lnAf           = (float*)alloc((size_t)BT * NHEADS * 4);
  unsigned short* xbc   = (unsigned short*)alloc((size_t)BT * CONVCH * 2);
  unsigned short* bcb   = (unsigned short*)alloc((size_t)BT * 256 * 2);
  unsigned short* SL    = (unsigned short*)alloc((size_t)1024 * 64 * 128 * 2);
  unsigned short* y1buf = (unsigned short*)alloc((size_t)1024 * 64 * 64 * 2);
  float* dtot           = (float*)alloc((size_t)1024 * 4);
  unsigned short* yg    = (unsigned short*)alloc((size_t)BT * DINNER * 2);
  float* ssq            = (float*)alloc((size_t)BT * 4);
  unsigned short* hn    = (unsigned short*)alloc((size_t)BT * DIM * 2);
  unsigned short* Wp_b  = (unsigned short*)alloc((size_t)2 * DINPROJ * DIM * 2);
  unsigned short* Wo_b  = (unsigned short*)alloc((size_t)2 * DIM * DINNER * 2);
  unsigned short* emb_b = (unsigned short*)alloc((size_t)256 * DIM * 2 + 256);

  // fused prologue: 3x weight cvt (gw folded into Wo) + embed in ONE launch
  prologue_k<<<PRO_BLK, 256, 0, stream>>>(Wp, Wo, emb, gw, Wp_b, Wo_b, emb_b, x, h_f32, hb);

  for (int l = 0; l < 2; ++l) {
    const unsigned short* Wpl = Wp_b + (size_t)l * DINPROJ * DIM;
    const unsigned short* Wol = Wo_b + (size_t)l * DIM * DINNER;
    const float* cwl   = cw + (size_t)l * CONVCH * 4;
    const float* cbl   = cb + (size_t)l * CONVCH;
    const float* dtbl  = dtb + l * NHEADS;
    const float* alogl = alog + l * NHEADS;
    const float* Dwl   = Dw + l * NHEADS;

    gemm_bt<0, 128, 128, 32><<<dim3(35, 16), 256, 0, stream>>>(hb, Wpl, BT, DINPROJ, DIM, zx, dtraw, nullptr, nullptr);
    conv_k<<<BT, 256, 0, stream>>>(zx, cwl, cbl, xbc, bcb, dtraw, dtbl, alogl, dtf, lnAf, ssq);
    ssd_intra<<<1024, 256, 0, stream>>>(bcb, xbc, dtf, lnAf, y1buf, SL, dtot);
    ssd_state<<<512, 256, 0, stream>>>(SL, dtot);
    ssd_inter<<<1024, 256, 0, stream>>>(bcb, SL, y1buf, xbc, zx, lnAf, Dwl, yg, ssq);
    gemm_bt<1, 64, 64, 64><<<dim3(16, 32), 256, 0, stream>>>(yg, Wol, BT, DIM, DINNER, nullptr, h_f32, hb, ssq);
  }

  rmsfinal_k<<<BT, 256, 0, stream>>>(h_f32, fnw, hn);
  gemm_bt<2, 64, 64, 64><<<dim3(4, 32), 256, 0, stream>>>(hn, emb_b, BT, 256, DIM,
                                                          nullptr, (float*)d_out, nullptr, nullptr);
}

// Round 22
// 349.406 us; speedup vs baseline: 1.0553x; 1.0194x over previous
//
#include <hip/hip_runtime.h>
#include <hip/hip_bf16.h>

#define BT 2048
#define T_SEQ 1024
#define DIM 1024
#define DINNER 2048
#define DSTATE 128
#define HEADDIM 64
#define NHEADS 32
#define CONVCH 2304
#define DINPROJ 4384
#define EPS_F 1e-5f
#define NCHUNK 16   // T_SEQ / 64

typedef __bf16 bf16x8 __attribute__((ext_vector_type(8)));
typedef float f32x4 __attribute__((ext_vector_type(4)));

__device__ __forceinline__ float b2f(unsigned short u) {
  union { unsigned int i; float f; } v; v.i = ((unsigned int)u) << 16; return v.f;
}
__device__ __forceinline__ unsigned short f2b(float f) {
  unsigned int x = __float_as_uint(f);
  return (unsigned short)((x + 0x7fffu + ((x >> 16) & 1u)) >> 16);
}

// async global->LDS DMA (gemm staging)
__device__ __forceinline__ void gload_lds16(const void* g, void* l) {
  __builtin_amdgcn_global_load_lds(
      (const __attribute__((address_space(1))) unsigned int*)g,
      (__attribute__((address_space(3))) unsigned int*)l, 16, 0, 0);
}

// ---------------- fused prologue: 3x fp32->bf16 weight cvt + embed ----------
// r17-validated (-3 launches). r18: gw (RMSNorm gamma) folded into Wo_b.
#define NWP_ELEM (2 * DINPROJ * DIM)     // 8,978,432
#define NWO_ELEM (2 * DIM * DINNER)      // 4,194,304
#define NEM_ELEM (256 * DIM)             // 262,144
#define NWP_BLK (NWP_ELEM / 4 / 256)     // 8768
#define NWO_BLK (NWO_ELEM / 4 / 256)     // 4096
#define NEM_BLK (NEM_ELEM / 4 / 256)     // 256
#define PRO_BLK (NWP_BLK + NWO_BLK + NEM_BLK + BT)   // 15168

__global__ void prologue_k(const float* __restrict__ Wp, const float* __restrict__ Wo,
                           const float* __restrict__ emb, const float* __restrict__ gw,
                           unsigned short* __restrict__ Wp_b,
                           unsigned short* __restrict__ Wo_b,
                           unsigned short* __restrict__ emb_b,
                           const int* __restrict__ x,
                           float* __restrict__ h, unsigned short* __restrict__ hb) {
  int bid = blockIdx.x;
  if (bid < NWP_BLK) {
    int i = (bid * 256 + threadIdx.x) * 4;
    float4 v = *(const float4*)(Wp + i);
    Wp_b[i + 0] = f2b(v.x); Wp_b[i + 1] = f2b(v.y);
    Wp_b[i + 2] = f2b(v.z); Wp_b[i + 3] = f2b(v.w);
  } else if (bid < NWP_BLK + NWO_BLK) {
    int i = ((bid - NWP_BLK) * 256 + threadIdx.x) * 4;
    int li = i / (DIM * DINNER);
    int kk = i & (DINNER - 1);          // i % DINNER (i multiple of 4, no wrap)
    float4 v = *(const float4*)(Wo + i);
    float4 g = *(const float4*)(gw + li * DINNER + kk);
    Wo_b[i + 0] = f2b(v.x * g.x); Wo_b[i + 1] = f2b(v.y * g.y);
    Wo_b[i + 2] = f2b(v.z * g.z); Wo_b[i + 3] = f2b(v.w * g.w);
  } else if (bid < NWP_BLK + NWO_BLK + NEM_BLK) {
    int i = ((bid - NWP_BLK - NWO_BLK) * 256 + threadIdx.x) * 4;
    float4 v = *(const float4*)(emb + i);
    emb_b[i + 0] = f2b(v.x); emb_b[i + 1] = f2b(v.y);
    emb_b[i + 2] = f2b(v.z); emb_b[i + 3] = f2b(v.w);
  } else {
    int t = bid - (NWP_BLK + NWO_BLK + NEM_BLK);
    int tok = x[t];
    int d = threadIdx.x;
#pragma unroll
    for (int j = 0; j < 4; ++j, d += 256) {
      float v = emb[(size_t)tok * DIM + d];
      h[(size_t)t * DIM + d] = v;
      hb[(size_t)t * DIM + d] = f2b(v);
    }
  }
}

// ---------------- GEMM: C[M,N] = A[M,K] * Bw[N,K]^T (bf16, fp32 acc) ----------------
// r9-validated 2-phase dbuf structure; T1 XCD column-major swizzle.
// BK templated (drain-count model, validated r10/r21 both directions):
//   gemm<0> 128^2 BK=32  (BK=64 refuted r10: 64KB LDS cuts residency)
//   gemm<1> 64^2  BK=128 (r22: LDS 64KB -> cap 2/CU == grid 2.0/CU,
//     residency-NEUTRAL; drains 32->16 over K=2048; r21's BK=64 gave -8us)
//   gemm<2> 64^2  BK=64  (r21-validated)
// BK>=64 needs the 16B-slot XOR swizzle (slot ^= row&(BK/8-1)); mechanics
// verified conflict-free r10/r21. MODE==1 applies fused RMSNorm row-scale.
template <int MODE, int TM, int TN, int BK>
__global__ __launch_bounds__(256) void gemm_bt(
    const unsigned short* __restrict__ A,
    const unsigned short* __restrict__ Bw,
    int M, int N, int K,
    unsigned short* __restrict__ Cout,
    float* __restrict__ aux,
    unsigned short* __restrict__ aux2,
    const float* __restrict__ ssq) {
  constexpr int FM = TM / 32, FN = TN / 32;
  constexpr int RPC = 2048 / BK;           // rows per 4KB staging chunk
  constexpr int CA = TM / RPC, CB = TN / RPC;
  constexpr int KK = BK / 32;              // mfma k-slices per K-step
  constexpr int SPR = BK / 8;              // 16B slots per row
  constexpr int TPR = BK / 8;              // staging threads per row
  constexpr int SMASK = (BK >= 64) ? (BK / 8 - 1) : 0;
  constexpr int HA = TM * BK, HB = TN * BK;   // elements per buffer
  __shared__ __align__(16) unsigned short As[2 * HA];
  __shared__ __align__(16) unsigned short Bs[2 * HB];
  const int tid = threadIdx.x;
  const int lane = tid & 63;
  const int wave = tid >> 6;

  // bijective XCD remap (m204): column-major chunks per XCD for B-panel L2 reuse.
  const int gx = gridDim.x, gy = gridDim.y;
  const int nwg = gx * gy;
  const int orig = (int)(blockIdx.y * gx + blockIdx.x);
  const int q = nwg >> 3, rr = nwg & 7;
  const int xcd = orig & 7, idx = orig >> 3;
  const int swz = (xcd < rr ? xcd * (q + 1) : rr * (q + 1) + (xcd - rr) * q) + idx;
  const int bxs = swz / gy;          // n-tile (column-major walk)
  const int bys = swz - bxs * gy;    // m-tile
  const int m0 = bys * TM;
  const int n0 = bxs * TN;

  const int wm = (wave >> 1) * (TM / 2);
  const int wn = (wave & 1) * (TN / 2);
  const int quad = lane >> 4;
  const int r = lane & 15;
  const int sa = r & SMASK;          // read-side swizzle key (row&SMASK == r&SMASK)

  f32x4 acc[FM][FN];
#pragma unroll
  for (int i = 0; i < FM; ++i)
#pragma unroll
    for (int j = 0; j < FN; ++j) acc[i][j] = f32x4{0.f, 0.f, 0.f, 0.f};

  // staging: thread tid fills row (tid/TPR), slot (tid%TPR) of each chunk.
  // BK>=64: global column pre-swizzled so LDS slot s holds global slot
  // s^(row&SMASK) (involution; read applies the same XOR). LDS dest stays
  // linear (rule #21: gload_lds writes base+lane*16).
  const int rowt = tid / TPR;
  int colb = tid % TPR;
  if (BK >= 64) colb ^= (rowt & SMASK);
  const int colt = colb * 8;
  const unsigned short* aG[CA];
  unsigned short* aD[CA];
  const unsigned short* bG[CB];
  unsigned short* bD[CB];
#pragma unroll
  for (int j = 0; j < CA; ++j) {
    aG[j] = A + (size_t)(m0 + j * RPC + rowt) * K + colt;
    aD[j] = As + wave * 512 + j * 2048;
  }
#pragma unroll
  for (int j = 0; j < CB; ++j) {
    int rb = n0 + j * RPC + rowt; if (rb >= N) rb = N - 1;
    bG[j] = Bw + (size_t)rb * K + colt;
    bD[j] = Bs + wave * 512 + j * 2048;
  }

  // prologue: stage K-tile 0 into buffer 0
#pragma unroll
  for (int j = 0; j < CA; ++j) gload_lds16(aG[j], aD[j]);
#pragma unroll
  for (int j = 0; j < CB; ++j) gload_lds16(bG[j], bD[j]);
  __syncthreads();   // drains vmcnt(0) -> buffer 0 visible

  int cur = 0;
  for (int k0 = 0; k0 < K; k0 += BK) {
    const int nxt = cur ^ 1;
    // issue prefetch of next K-tile into the other buffer (in flight during MFMA)
    if (k0 + BK < K) {
#pragma unroll
      for (int j = 0; j < CA; ++j) gload_lds16(aG[j] + k0 + BK, aD[j] + nxt * HA);
#pragma unroll
      for (int j = 0; j < CB; ++j) gload_lds16(bG[j] + k0 + BK, bD[j] + nxt * HB);
    }
    const bf16x8* ap = (const bf16x8*)(As + cur * HA);
    const bf16x8* bp = (const bf16x8*)(Bs + cur * HB);
    bf16x8 af[KK][FM], bfr[KK][FN];
#pragma unroll
    for (int kk = 0; kk < KK; ++kk) {
      const int slot = (kk * 4 + quad) ^ sa;
#pragma unroll
      for (int mt = 0; mt < FM; ++mt)
        af[kk][mt] = ap[(wm + mt * 16 + r) * SPR + slot];
#pragma unroll
      for (int nt = 0; nt < FN; ++nt)
        bfr[kk][nt] = bp[(wn + nt * 16 + r) * SPR + slot];
    }
#pragma unroll
    for (int kk = 0; kk < KK; ++kk)
#pragma unroll
      for (int mt = 0; mt < FM; ++mt)
#pragma unroll
        for (int nt = 0; nt < FN; ++nt)
          acc[mt][nt] = __builtin_amdgcn_mfma_f32_16x16x32_bf16(af[kk][mt], bfr[kk][nt], acc[mt][nt], 0, 0, 0);
    __syncthreads();  // drains prefetch (hidden under MFMA) + read-done fence
    cur = nxt;
  }

#pragma unroll
  for (int mt = 0; mt < FM; ++mt) {
#pragma unroll
    for (int nt = 0; nt < FN; ++nt) {
#pragma unroll
      for (int i = 0; i < 4; ++i) {
        int gm = m0 + wm + mt * 16 + quad * 4 + i;
        int gn = n0 + wn + nt * 16 + r;
        if (gn < N) {
          float v = acc[mt][nt][i];
          if (MODE == 0) {
            Cout[(size_t)gm * N + gn] = f2b(v);
            if (gn >= DINNER + CONVCH)
              aux[(size_t)gm * NHEADS + (gn - (DINNER + CONVCH))] = v;
          } else if (MODE == 1) {
            float scl = rsqrtf(ssq[gm] * (1.f / DINNER) + EPS_F);
            size_t o = (size_t)gm * N + gn;
            float hnv = aux[o] + v * scl;
            aux[o] = hnv;
            aux2[o] = f2b(hnv);
          } else {
            aux[(size_t)gm * N + gn] = v;
          }
        }
      }
    }
  }
}

// ---------------- causal conv (K=4) + silu, with fused dt/lnA ----------------
// r9 scalar form (measured best). r18: thread 0 zeroes ssq[t].
__global__ void conv_k(const unsigned short* __restrict__ zx,
                       const float* __restrict__ cw,
                       const float* __restrict__ cb,
                       unsigned short* __restrict__ xbc,
                       unsigned short* __restrict__ bcb,
                       const float* __restrict__ dtraw,
                       const float* __restrict__ dtb,
                       const float* __restrict__ alog,
                       float* __restrict__ dtf,
                       float* __restrict__ lnAf,
                       float* __restrict__ ssq) {
  int t = blockIdx.x;
  int tt = t & (T_SEQ - 1);
  if (threadIdx.x == 0) ssq[t] = 0.f;
  if (threadIdx.x < NHEADS) {
    int h = threadIdx.x;
    float xx = dtraw[t * NHEADS + h] + dtb[h];
    float sp = (xx > 20.f) ? xx : log1pf(expf(xx));
    dtf[t * NHEADS + h] = sp;
    lnAf[t * NHEADS + h] = -sp * expf(alog[h]);
  }
  for (int c = threadIdx.x; c < CONVCH; c += 256) {
    float acc = cb[c];
#pragma unroll
    for (int k = 0; k < 4; ++k) {
      int tp = tt - 3 + k;
      if (tp >= 0)
        acc += b2f(zx[(size_t)(t - 3 + k) * DINPROJ + DINNER + c]) * cw[c * 4 + k];
    }
    float s = acc / (1.f + expf(-acc));
    unsigned short sb = f2b(s);
    xbc[(size_t)t * CONVCH + c] = sb;
    if (c >= DINNER) bcb[(size_t)t * 256 + (c - DINNER)] = sb;
  }
}

// ---------------- SSD pass 1: intra-chunk (per (b,h,chunk)) ----------------
// r8 (validated): wsL precompute + BWT cooperative transpose.
__global__ __launch_bounds__(256) void ssd_intra(
    const unsigned short* __restrict__ bcb,
    const unsigned short* __restrict__ xbc,
    const float* __restrict__ dtf, const float* __restrict__ lnAf,
    unsigned short* __restrict__ y1buf, unsigned short* __restrict__ SL,
    float* __restrict__ dtot) {
  const int bi = blockIdx.x;           // ((b*32+h)*16 + c), 1024 blocks
  const int c = bi & 15;
  const int h = (bi >> 4) & 31;
  const int b = bi >> 9;
  const int tid = threadIdx.x;
  const int w = tid >> 6, l = tid & 63, r = l & 15, quad = l >> 4;
  const size_t tok0 = (size_t)b * T_SEQ + c * 64;

  __shared__ __align__(16) unsigned short BCs[64 * 264];  // [t][B0..127|C128..255]+pad
  __shared__ __align__(16) unsigned short Xrow[64 * 72];  // [u][p]
  __shared__ __align__(16) unsigned short XTs[64 * 72];   // [p][u]
  __shared__ __align__(16) unsigned short BWT[128 * 72];  // [n][u] = ws[u]*B[u][n]
  __shared__ __align__(16) unsigned short Ms[64 * 72];    // [t][u]
  __shared__ float cumL[64], dtL[64], wsL[64];

#pragma unroll
  for (int i = 0; i < 8; ++i) {
    int idx = tid + i * 256;
    int row = idx >> 5, col = (idx & 31) * 8;
    uint4 v = *(const uint4*)(bcb + (tok0 + row) * 256 + col);
    *(uint4*)(BCs + row * 264 + col) = v;
  }
  // x tile: rows = tokens (coalesced 128B from xbc), cols = p
#pragma unroll
  for (int i = 0; i < 2; ++i) {
    int idx = tid + i * 256;
    int u = idx >> 3, pc = (idx & 7) * 8;
    uint4 v = *(const uint4*)(xbc + (tok0 + u) * CONVCH + h * HEADDIM + pc);
    *(uint4*)(Xrow + u * 72 + pc) = v;
  }
  if (tid < 64) {
    float dt = dtf[(tok0 + tid) * NHEADS + h];
    float v = lnAf[(tok0 + tid) * NHEADS + h];
    dtL[tid] = dt;
#pragma unroll
    for (int off = 1; off < 64; off <<= 1) {
      float u = __shfl_up(v, off, 64);
      if (tid >= off) v += u;
    }
    cumL[tid] = v;
    float tot = __shfl(v, 63, 64);   // scan total, in-wave broadcast
    wsL[tid] = dt * expf(tot - v);   // ws[u] = dt[u]*exp(cum63-cum[u]), once
    if (tid == 63) dtot[bi] = expf(tot);
  }
  __syncthreads();

  // in-LDS transpose: XTs[p][u] = x
#pragma unroll
  for (int i = 0; i < 2; ++i) {
    int idx = tid + i * 256;
    int p = idx >> 3, ug = (idx & 7) * 8;
    unsigned short tA[8];
#pragma unroll
    for (int j = 0; j < 8; ++j) tA[j] = Xrow[(ug + j) * 72 + p];
    *(uint4*)(XTs + p * 72 + ug) = *(uint4*)tA;
  }

  // cooperative B-transpose with ws fold: BWT[n][u] = ws[u]*B[u][n]
  {
    const int n = tid >> 1;
    const int ug = (tid & 1) * 32;
    unsigned short eb[32];
#pragma unroll
    for (int j = 0; j < 32; ++j)
      eb[j] = f2b(b2f(BCs[(ug + j) * 264 + n]) * wsL[ug + j]);
#pragma unroll
    for (int qq = 0; qq < 4; ++qq)
      *(uint4*)(BWT + n * 72 + ug + qq * 8) = *(uint4*)(eb + qq * 8);
  }

  // GEMM1: G = C·B^T  (64x64, K=128)
  f32x4 g[4];
#pragma unroll
  for (int nt = 0; nt < 4; ++nt) g[nt] = f32x4{0.f, 0.f, 0.f, 0.f};
#pragma unroll
  for (int kk = 0; kk < 4; ++kk) {
    bf16x8 afr = *(const bf16x8*)(BCs + (w * 16 + r) * 264 + 128 + kk * 32 + quad * 8);
#pragma unroll
    for (int nt = 0; nt < 4; ++nt) {
      bf16x8 bfr = *(const bf16x8*)(BCs + (nt * 16 + r) * 264 + kk * 32 + quad * 8);
      g[nt] = __builtin_amdgcn_mfma_f32_16x16x32_bf16(afr, bfr, g[nt], 0, 0, 0);
    }
  }
#pragma unroll
  for (int nt = 0; nt < 4; ++nt) {
#pragma unroll
    for (int i = 0; i < 4; ++i) {
      int t_ = w * 16 + quad * 4 + i;
      int u_ = nt * 16 + r;
      float wv = (u_ <= t_) ? expf(cumL[t_] - cumL[u_]) * dtL[u_] : 0.f;
      Ms[t_ * 72 + u_] = f2b(g[nt][i] * wv);
    }
  }
  __syncthreads();   // fences Ms, XTs, BWT writes -> GEMM2/GEMM3 reads

  // GEMM2: Y1 = M·X  (64t x 64p, K=64u)
  f32x4 y1[4];
#pragma unroll
  for (int nt = 0; nt < 4; ++nt) y1[nt] = f32x4{0.f, 0.f, 0.f, 0.f};
#pragma unroll
  for (int kk = 0; kk < 2; ++kk) {
    bf16x8 afr = *(const bf16x8*)(Ms + (w * 16 + r) * 72 + kk * 32 + quad * 8);
#pragma unroll
    for (int nt = 0; nt < 4; ++nt) {
      bf16x8 bfr = *(const bf16x8*)(XTs + (nt * 16 + r) * 72 + kk * 32 + quad * 8);
      y1[nt] = __builtin_amdgcn_mfma_f32_16x16x32_bf16(afr, bfr, y1[nt], 0, 0, 0);
    }
  }
#pragma unroll
  for (int nt = 0; nt < 4; ++nt)
#pragma unroll
    for (int i = 0; i < 4; ++i) {
      int t_ = w * 16 + quad * 4 + i, p_ = nt * 16 + r;
      y1buf[((size_t)bi * 64 + t_) * 64 + p_] = f2b(y1[nt][i]);
    }

  // GEMM3: Slocal[p][n] = sum_u XTs[p][u] * BWT[n][u]  (64p x 128n, K=64u)
  f32x4 sl[8];
#pragma unroll
  for (int nt = 0; nt < 8; ++nt) sl[nt] = f32x4{0.f, 0.f, 0.f, 0.f};
#pragma unroll
  for (int kk = 0; kk < 2; ++kk) {
    bf16x8 afr = *(const bf16x8*)(XTs + (w * 16 + r) * 72 + kk * 32 + quad * 8);
#pragma unroll
    for (int nt = 0; nt < 8; ++nt) {
      bf16x8 bfr = *(const bf16x8*)(BWT + (nt * 16 + r) * 72 + kk * 32 + quad * 8);
      sl[nt] = __builtin_amdgcn_mfma_f32_16x16x32_bf16(afr, bfr, sl[nt], 0, 0, 0);
    }
  }
#pragma unroll
  for (int nt = 0; nt < 8; ++nt)
#pragma unroll
    for (int i = 0; i < 4; ++i) {
      int p_ = w * 16 + quad * 4 + i, n_ = nt * 16 + r;
      SL[((size_t)bi * 64 + p_) * 128 + n_] = f2b(sl[nt][i]);
    }
}

// ---------------- SSD pass 2: chunk-state recurrence (in-place Slocal -> Spre) --------
__global__ void ssd_state(unsigned short* __restrict__ SL,
                          const float* __restrict__ dtot) {
  int gidx = blockIdx.x * 256 + threadIdx.x;   // 131072 = 64bh * 64p * 32(n/4)
  int n4 = (gidx & 31) * 4;
  int p = (gidx >> 5) & 63;
  int bh = gidx >> 11;
  float sx = 0.f, sy = 0.f, sz = 0.f, sw = 0.f;
  for (int c = 0; c < NCHUNK; ++c) {
    size_t off = ((size_t)(bh * 16 + c) * 64 + p) * 128 + n4;
    uint2 lv = *(uint2*)(SL + off);
    float d = dtot[bh * 16 + c];
    uint2 sv;
    sv.x = (unsigned)f2b(sx) | ((unsigned)f2b(sy) << 16);
    sv.y = (unsigned)f2b(sz) | ((unsigned)f2b(sw) << 16);
    *(uint2*)(SL + off) = sv;           // state BEFORE chunk c
    sx = d * sx + b2f(lv.x & 0xffff);
    sy = d * sy + b2f(lv.x >> 16);
    sz = d * sz + b2f(lv.y & 0xffff);
    sw = d * sw + b2f(lv.y >> 16);
  }
}

// ---------------- SSD pass 3: inter-chunk + combine + gate ----------------
// r18: accumulates per-token sum-of-squares of the gated f32 output into
// ssq[tok] (2 shfl + 1 atomicAdd per token per block) for the fused RMSNorm
// in gemm<1>'s epilogue.
__global__ __launch_bounds__(256) void ssd_inter(
    const unsigned short* __restrict__ bcb,
    const unsigned short* __restrict__ SL,       // holds Spre now
    const unsigned short* __restrict__ y1buf,
    const unsigned short* __restrict__ xbc,
    const unsigned short* __restrict__ zx,
    const float* __restrict__ lnAf,
    const float* __restrict__ Dw,
    unsigned short* __restrict__ yg,
    float* __restrict__ ssq) {
  const int bi = blockIdx.x;
  const int c = bi & 15, h = (bi >> 4) & 31, b = bi >> 9;
  const int tid = threadIdx.x;
  const int w = tid >> 6, l = tid & 63, r = l & 15, quad = l >> 4;
  const size_t tok0 = (size_t)b * T_SEQ + c * 64;

  __shared__ __align__(16) unsigned short Cs[64 * 136];
  __shared__ __align__(16) unsigned short Sp[64 * 136];
  __shared__ __align__(16) float Yf[64 * 68];
  __shared__ float cumL[64];

#pragma unroll
  for (int i = 0; i < 4; ++i) {
    int idx = tid + i * 256;
    int row = idx >> 4, col = (idx & 15) * 8;
    uint4 v = *(const uint4*)(bcb + (tok0 + row) * 256 + 128 + col);
    *(uint4*)(Cs + row * 136 + col) = v;
    uint4 s = *(const uint4*)(SL + ((size_t)bi * 64 + row) * 128 + col);
    *(uint4*)(Sp + row * 136 + col) = s;
  }
  if (tid < 64) {
    float v = lnAf[(tok0 + tid) * NHEADS + h];
#pragma unroll
    for (int off = 1; off < 64; off <<= 1) {
      float u = __shfl_up(v, off, 64);
      if (tid >= off) v += u;
    }
    cumL[tid] = v;
  }
  __syncthreads();

  // Yi[t][p] = sum_n C[t][n]*Spre[p][n]  (K=128)
  f32x4 yi[4];
#pragma unroll
  for (int nt = 0; nt < 4; ++nt) yi[nt] = f32x4{0.f, 0.f, 0.f, 0.f};
#pragma unroll
  for (int kk = 0; kk < 4; ++kk) {
    bf16x8 afr = *(const bf16x8*)(Cs + (w * 16 + r) * 136 + kk * 32 + quad * 8);
#pragma unroll
    for (int nt = 0; nt < 4; ++nt) {
      bf16x8 bfr = *(const bf16x8*)(Sp + (nt * 16 + r) * 136 + kk * 32 + quad * 8);
      yi[nt] = __builtin_amdgcn_mfma_f32_16x16x32_bf16(afr, bfr, yi[nt], 0, 0, 0);
    }
  }
#pragma unroll
  for (int nt = 0; nt < 4; ++nt)
#pragma unroll
    for (int i = 0; i < 4; ++i) {
      int t_ = w * 16 + quad * 4 + i, p_ = nt * 16 + r;
      float y1 = b2f(y1buf[((size_t)bi * 64 + t_) * 64 + p_]);
      Yf[t_ * 68 + p_] = y1 + expf(cumL[t_]) * yi[nt][i];
    }
  __syncthreads();

  // combine: y = Yf + D*x, gate with silu(z), write yg + accumulate ssq
  const float Dh = Dw[h];
  const int t_ = tid >> 2, pg = (tid & 3) * 16;
  const size_t tok = tok0 + t_;
  union { uint4 q[2]; unsigned short u[16]; } xv, zv, ov;
  xv.q[0] = *(const uint4*)(xbc + tok * CONVCH + h * 64 + pg);
  xv.q[1] = *(const uint4*)(xbc + tok * CONVCH + h * 64 + pg + 8);
  zv.q[0] = *(const uint4*)(zx + tok * DINPROJ + h * 64 + pg);
  zv.q[1] = *(const uint4*)(zx + tok * DINPROJ + h * 64 + pg + 8);
  float ssf = 0.f;
#pragma unroll
  for (int j = 0; j < 16; ++j) {
    float y = Yf[t_ * 68 + pg + j] + Dh * b2f(xv.u[j]);
    float zf = b2f(zv.u[j]);
    float yg_f = y * (zf / (1.f + expf(-zf)));
    ov.u[j] = f2b(yg_f);
    ssf += yg_f * yg_f;
  }
  *(uint4*)(yg + tok * DINNER + h * 64 + pg) = ov.q[0];
  *(uint4*)(yg + tok * DINNER + h * 64 + pg + 8) = ov.q[1];
  // reduce the 4 lanes of this token, one atomic per token per block
  ssf += __shfl_xor(ssf, 1, 64);
  ssf += __shfl_xor(ssf, 2, 64);
  if ((tid & 3) == 0) atomicAdd(&ssq[tok], ssf);
}

// ---------------- final RMSNorm over 1024 ----------------
__global__ void rmsfinal_k(const float* __restrict__ hf,
                           const float* __restrict__ w,
                           unsigned short* __restrict__ out) {
  int t = blockIdx.x;
  int base = threadIdx.x * 4;
  float4 v = *(const float4*)(hf + (size_t)t * DIM + base);
  float ss = v.x * v.x + v.y * v.y + v.z * v.z + v.w * v.w;
#pragma unroll
  for (int o = 32; o > 0; o >>= 1) ss += __shfl_xor(ss, o, 64);
  __shared__ float red[4];
  if ((threadIdx.x & 63) == 0) red[threadIdx.x >> 6] = ss;
  __syncthreads();
  ss = red[0] + red[1] + red[2] + red[3];
  float scale = rsqrtf(ss * (1.f / DIM) + EPS_F);
  out[(size_t)t * DIM + base + 0] = f2b(v.x * scale * w[base + 0]);
  out[(size_t)t * DIM + base + 1] = f2b(v.y * scale * w[base + 1]);
  out[(size_t)t * DIM + base + 2] = f2b(v.z * scale * w[base + 2]);
  out[(size_t)t * DIM + base + 3] = f2b(v.w * scale * w[base + 3]);
}

extern "C" void kernel_launch(void* const* d_in, const int* in_sizes, int n_in,
                              void* d_out, int out_size, void* d_ws, size_t ws_size,
                              hipStream_t stream) {
  const int*   x    = (const int*)d_in[0];
  const float* emb  = (const float*)d_in[1];
  const float* Wp   = (const float*)d_in[2];
  const float* cw   = (const float*)d_in[3];
  const float* cb   = (const float*)d_in[4];
  const float* dtb  = (const float*)d_in[5];
  const float* alog = (const float*)d_in[6];
  const float* Dw   = (const float*)d_in[7];
  const float* gw   = (const float*)d_in[8];
  const float* Wo   = (const float*)d_in[9];
  const float* fnw  = (const float*)d_in[10];

  char* w = (char*)d_ws;
  auto alloc = [&](size_t bytes) {
    char* p = w; w += (bytes + 255) & ~(size_t)255; return p;
  };
  float* h_f32          = (float*)alloc((size_t)BT * DIM * 4);
  unsigned short* hb    = (unsigned short*)alloc((size_t)BT * DIM * 2);
  unsigned short* zx    = (unsigned short*)alloc((size_t)BT * DINPROJ * 2);
  float* dtraw          = (float*)alloc((size_t)BT * NHEADS * 4);
  float* dtf            = (float*)alloc((size_t)BT * NHEADS * 4);
  float* lnAf           = (float*)alloc((size_t)BT * NHEADS * 4);
  unsigned short* xbc   = (unsigned short*)alloc((size_t)BT * CONVCH * 2);
  unsigned short* bcb   = (unsigned short*)alloc((size_t)BT * 256 * 2);
  unsigned short* SL    = (unsigned short*)alloc((size_t)1024 * 64 * 128 * 2);
  unsigned short* y1buf = (unsigned short*)alloc((size_t)1024 * 64 * 64 * 2);
  float* dtot           = (float*)alloc((size_t)1024 * 4);
  unsigned short* yg    = (unsigned short*)alloc((size_t)BT * DINNER * 2);
  float* ssq            = (float*)alloc((size_t)BT * 4);
  unsigned short* hn    = (unsigned short*)alloc((size_t)BT * DIM * 2);
  unsigned short* Wp_b  = (unsigned short*)alloc((size_t)2 * DINPROJ * DIM * 2);
  unsigned short* Wo_b  = (unsigned short*)alloc((size_t)2 * DIM * DINNER * 2);
  unsigned short* emb_b = (unsigned short*)alloc((size_t)256 * DIM * 2 + 256);

  // fused prologue: 3x weight cvt (gw folded into Wo) + embed in ONE launch
  prologue_k<<<PRO_BLK, 256, 0, stream>>>(Wp, Wo, emb, gw, Wp_b, Wo_b, emb_b, x, h_f32, hb);

  for (int l = 0; l < 2; ++l) {
    const unsigned short* Wpl = Wp_b + (size_t)l * DINPROJ * DIM;
    const unsigned short* Wol = Wo_b + (size_t)l * DIM * DINNER;
    const float* cwl   = cw + (size_t)l * CONVCH * 4;
    const float* cbl   = cb + (size_t)l * CONVCH;
    const float* dtbl  = dtb + l * NHEADS;
    const float* alogl = alog + l * NHEADS;
    const float* Dwl   = Dw + l * NHEADS;

    gemm_bt<0, 128, 128, 32><<<dim3(35, 16), 256, 0, stream>>>(hb, Wpl, BT, DINPROJ, DIM, zx, dtraw, nullptr, nullptr);
    conv_k<<<BT, 256, 0, stream>>>(zx, cwl, cbl, xbc, bcb, dtraw, dtbl, alogl, dtf, lnAf, ssq);
    ssd_intra<<<1024, 256, 0, stream>>>(bcb, xbc, dtf, lnAf, y1buf, SL, dtot);
    ssd_state<<<512, 256, 0, stream>>>(SL, dtot);
    ssd_inter<<<1024, 256, 0, stream>>>(bcb, SL, y1buf, xbc, zx, lnAf, Dwl, yg, ssq);
    gemm_bt<1, 64, 64, 128><<<dim3(16, 32), 256, 0, stream>>>(yg, Wol, BT, DIM, DINNER, nullptr, h_f32, hb, ssq);
  }

  rmsfinal_k<<<BT, 256, 0, stream>>>(h_f32, fnw, hn);
  gemm_bt<2, 64, 64, 64><<<dim3(4, 32), 256, 0, stream>>>(hn, emb_b, BT, 256, DIM,
                                                          nullptr, (float*)d_out, nullptr, nullptr);
}

// Round 23
// 345.949 us; speedup vs baseline: 1.0659x; 1.0100x over previous
//
#include <hip/hip_runtime.h>
#include <hip/hip_bf16.h>

#define BT 2048
#define T_SEQ 1024
#define DIM 1024
#define DINNER 2048
#define DSTATE 128
#define HEADDIM 64
#define NHEADS 32
#define CONVCH 2304
#define DINPROJ 4384
#define EPS_F 1e-5f
#define NCHUNK 16   // T_SEQ / 64

typedef __bf16 bf16x8 __attribute__((ext_vector_type(8)));
typedef float f32x4 __attribute__((ext_vector_type(4)));

__device__ __forceinline__ float b2f(unsigned short u) {
  union { unsigned int i; float f; } v; v.i = ((unsigned int)u) << 16; return v.f;
}
__device__ __forceinline__ unsigned short f2b(float f) {
  unsigned int x = __float_as_uint(f);
  return (unsigned short)((x + 0x7fffu + ((x >> 16) & 1u)) >> 16);
}

// async global->LDS DMA (gemm staging)
__device__ __forceinline__ void gload_lds16(const void* g, void* l) {
  __builtin_amdgcn_global_load_lds(
      (const __attribute__((address_space(1))) unsigned int*)g,
      (__attribute__((address_space(3))) unsigned int*)l, 16, 0, 0);
}

// ---------------- fused prologue: 3x fp32->bf16 weight cvt + embed ----------
// r17-validated (-3 launches). r18: gw (RMSNorm gamma) folded into Wo_b.
#define NWP_ELEM (2 * DINPROJ * DIM)     // 8,978,432
#define NWO_ELEM (2 * DIM * DINNER)      // 4,194,304
#define NEM_ELEM (256 * DIM)             // 262,144
#define NWP_BLK (NWP_ELEM / 4 / 256)     // 8768
#define NWO_BLK (NWO_ELEM / 4 / 256)     // 4096
#define NEM_BLK (NEM_ELEM / 4 / 256)     // 256
#define PRO_BLK (NWP_BLK + NWO_BLK + NEM_BLK + BT)   // 15168

__global__ void prologue_k(const float* __restrict__ Wp, const float* __restrict__ Wo,
                           const float* __restrict__ emb, const float* __restrict__ gw,
                           unsigned short* __restrict__ Wp_b,
                           unsigned short* __restrict__ Wo_b,
                           unsigned short* __restrict__ emb_b,
                           const int* __restrict__ x,
                           float* __restrict__ h, unsigned short* __restrict__ hb) {
  int bid = blockIdx.x;
  if (bid < NWP_BLK) {
    int i = (bid * 256 + threadIdx.x) * 4;
    float4 v = *(const float4*)(Wp + i);
    Wp_b[i + 0] = f2b(v.x); Wp_b[i + 1] = f2b(v.y);
    Wp_b[i + 2] = f2b(v.z); Wp_b[i + 3] = f2b(v.w);
  } else if (bid < NWP_BLK + NWO_BLK) {
    int i = ((bid - NWP_BLK) * 256 + threadIdx.x) * 4;
    int li = i / (DIM * DINNER);
    int kk = i & (DINNER - 1);          // i % DINNER (i multiple of 4, no wrap)
    float4 v = *(const float4*)(Wo + i);
    float4 g = *(const float4*)(gw + li * DINNER + kk);
    Wo_b[i + 0] = f2b(v.x * g.x); Wo_b[i + 1] = f2b(v.y * g.y);
    Wo_b[i + 2] = f2b(v.z * g.z); Wo_b[i + 3] = f2b(v.w * g.w);
  } else if (bid < NWP_BLK + NWO_BLK + NEM_BLK) {
    int i = ((bid - NWP_BLK - NWO_BLK) * 256 + threadIdx.x) * 4;
    float4 v = *(const float4*)(emb + i);
    emb_b[i + 0] = f2b(v.x); emb_b[i + 1] = f2b(v.y);
    emb_b[i + 2] = f2b(v.z); emb_b[i + 3] = f2b(v.w);
  } else {
    int t = bid - (NWP_BLK + NWO_BLK + NEM_BLK);
    int tok = x[t];
    int d = threadIdx.x;
#pragma unroll
    for (int j = 0; j < 4; ++j, d += 256) {
      float v = emb[(size_t)tok * DIM + d];
      h[(size_t)t * DIM + d] = v;
      hb[(size_t)t * DIM + d] = f2b(v);
    }
  }
}

// ---------------- GEMM: C[M,N] = A[M,K] * Bw[N,K]^T (bf16, fp32 acc) ----------------
// r9-validated 2-phase dbuf structure; T1 XCD column-major swizzle.
// BK templated (drain-count model: time ~ drains x exposed-latency, valid
// when residency-neutral; confirmed r10(-)/r21(+)/r22(+)):
//   gemm<0> 128^2 BK=32  (BK=64 refuted r10: 64KB LDS cuts residency 5->2)
//   gemm<1> 64^2  BK=128 (r22-validated: LDS 64KB cap 2/CU == grid 2.0/CU)
//   gemm<2> 64^2  BK=128 (r23: grid 0.5/CU, residency irrelevant; drains
//     16->8 over K=1024; same template cell as gemm<1>)
// BK>=64 needs the 16B-slot XOR swizzle (slot ^= row&(BK/8-1)); verified
// conflict-free r10/r21/r22. MODE==1 applies fused RMSNorm row-scale (r18).
template <int MODE, int TM, int TN, int BK>
__global__ __launch_bounds__(256) void gemm_bt(
    const unsigned short* __restrict__ A,
    const unsigned short* __restrict__ Bw,
    int M, int N, int K,
    unsigned short* __restrict__ Cout,
    float* __restrict__ aux,
    unsigned short* __restrict__ aux2,
    const float* __restrict__ ssq) {
  constexpr int FM = TM / 32, FN = TN / 32;
  constexpr int RPC = 2048 / BK;           // rows per 4KB staging chunk
  constexpr int CA = TM / RPC, CB = TN / RPC;
  constexpr int KK = BK / 32;              // mfma k-slices per K-step
  constexpr int SPR = BK / 8;              // 16B slots per row
  constexpr int TPR = BK / 8;              // staging threads per row
  constexpr int SMASK = (BK >= 64) ? (BK / 8 - 1) : 0;
  constexpr int HA = TM * BK, HB = TN * BK;   // elements per buffer
  __shared__ __align__(16) unsigned short As[2 * HA];
  __shared__ __align__(16) unsigned short Bs[2 * HB];
  const int tid = threadIdx.x;
  const int lane = tid & 63;
  const int wave = tid >> 6;

  // bijective XCD remap (m204): column-major chunks per XCD for B-panel L2 reuse.
  const int gx = gridDim.x, gy = gridDim.y;
  const int nwg = gx * gy;
  const int orig = (int)(blockIdx.y * gx + blockIdx.x);
  const int q = nwg >> 3, rr = nwg & 7;
  const int xcd = orig & 7, idx = orig >> 3;
  const int swz = (xcd < rr ? xcd * (q + 1) : rr * (q + 1) + (xcd - rr) * q) + idx;
  const int bxs = swz / gy;          // n-tile (column-major walk)
  const int bys = swz - bxs * gy;    // m-tile
  const int m0 = bys * TM;
  const int n0 = bxs * TN;

  const int wm = (wave >> 1) * (TM / 2);
  const int wn = (wave & 1) * (TN / 2);
  const int quad = lane >> 4;
  const int r = lane & 15;
  const int sa = r & SMASK;          // read-side swizzle key (row&SMASK == r&SMASK)

  f32x4 acc[FM][FN];
#pragma unroll
  for (int i = 0; i < FM; ++i)
#pragma unroll
    for (int j = 0; j < FN; ++j) acc[i][j] = f32x4{0.f, 0.f, 0.f, 0.f};

  // staging: thread tid fills row (tid/TPR), slot (tid%TPR) of each chunk.
  // BK>=64: global column pre-swizzled so LDS slot s holds global slot
  // s^(row&SMASK) (involution; read applies the same XOR). LDS dest stays
  // linear (rule #21: gload_lds writes base+lane*16).
  const int rowt = tid / TPR;
  int colb = tid % TPR;
  if (BK >= 64) colb ^= (rowt & SMASK);
  const int colt = colb * 8;
  const unsigned short* aG[CA];
  unsigned short* aD[CA];
  const unsigned short* bG[CB];
  unsigned short* bD[CB];
#pragma unroll
  for (int j = 0; j < CA; ++j) {
    aG[j] = A + (size_t)(m0 + j * RPC + rowt) * K + colt;
    aD[j] = As + wave * 512 + j * 2048;
  }
#pragma unroll
  for (int j = 0; j < CB; ++j) {
    int rb = n0 + j * RPC + rowt; if (rb >= N) rb = N - 1;
    bG[j] = Bw + (size_t)rb * K + colt;
    bD[j] = Bs + wave * 512 + j * 2048;
  }

  // prologue: stage K-tile 0 into buffer 0
#pragma unroll
  for (int j = 0; j < CA; ++j) gload_lds16(aG[j], aD[j]);
#pragma unroll
  for (int j = 0; j < CB; ++j) gload_lds16(bG[j], bD[j]);
  __syncthreads();   // drains vmcnt(0) -> buffer 0 visible

  int cur = 0;
  for (int k0 = 0; k0 < K; k0 += BK) {
    const int nxt = cur ^ 1;
    // issue prefetch of next K-tile into the other buffer (in flight during MFMA)
    if (k0 + BK < K) {
#pragma unroll
      for (int j = 0; j < CA; ++j) gload_lds16(aG[j] + k0 + BK, aD[j] + nxt * HA);
#pragma unroll
      for (int j = 0; j < CB; ++j) gload_lds16(bG[j] + k0 + BK, bD[j] + nxt * HB);
    }
    const bf16x8* ap = (const bf16x8*)(As + cur * HA);
    const bf16x8* bp = (const bf16x8*)(Bs + cur * HB);
    bf16x8 af[KK][FM], bfr[KK][FN];
#pragma unroll
    for (int kk = 0; kk < KK; ++kk) {
      const int slot = (kk * 4 + quad) ^ sa;
#pragma unroll
      for (int mt = 0; mt < FM; ++mt)
        af[kk][mt] = ap[(wm + mt * 16 + r) * SPR + slot];
#pragma unroll
      for (int nt = 0; nt < FN; ++nt)
        bfr[kk][nt] = bp[(wn + nt * 16 + r) * SPR + slot];
    }
#pragma unroll
    for (int kk = 0; kk < KK; ++kk)
#pragma unroll
      for (int mt = 0; mt < FM; ++mt)
#pragma unroll
        for (int nt = 0; nt < FN; ++nt)
          acc[mt][nt] = __builtin_amdgcn_mfma_f32_16x16x32_bf16(af[kk][mt], bfr[kk][nt], acc[mt][nt], 0, 0, 0);
    __syncthreads();  // drains prefetch (hidden under MFMA) + read-done fence
    cur = nxt;
  }

#pragma unroll
  for (int mt = 0; mt < FM; ++mt) {
#pragma unroll
    for (int nt = 0; nt < FN; ++nt) {
#pragma unroll
      for (int i = 0; i < 4; ++i) {
        int gm = m0 + wm + mt * 16 + quad * 4 + i;
        int gn = n0 + wn + nt * 16 + r;
        if (gn < N) {
          float v = acc[mt][nt][i];
          if (MODE == 0) {
            Cout[(size_t)gm * N + gn] = f2b(v);
            if (gn >= DINNER + CONVCH)
              aux[(size_t)gm * NHEADS + (gn - (DINNER + CONVCH))] = v;
          } else if (MODE == 1) {
            float scl = rsqrtf(ssq[gm] * (1.f / DINNER) + EPS_F);
            size_t o = (size_t)gm * N + gn;
            float hnv = aux[o] + v * scl;
            aux[o] = hnv;
            aux2[o] = f2b(hnv);
          } else {
            aux[(size_t)gm * N + gn] = v;
          }
        }
      }
    }
  }
}

// ---------------- causal conv (K=4) + silu, with fused dt/lnA ----------------
// r9 scalar form (measured best). r18: thread 0 zeroes ssq[t].
__global__ void conv_k(const unsigned short* __restrict__ zx,
                       const float* __restrict__ cw,
                       const float* __restrict__ cb,
                       unsigned short* __restrict__ xbc,
                       unsigned short* __restrict__ bcb,
                       const float* __restrict__ dtraw,
                       const float* __restrict__ dtb,
                       const float* __restrict__ alog,
                       float* __restrict__ dtf,
                       float* __restrict__ lnAf,
                       float* __restrict__ ssq) {
  int t = blockIdx.x;
  int tt = t & (T_SEQ - 1);
  if (threadIdx.x == 0) ssq[t] = 0.f;
  if (threadIdx.x < NHEADS) {
    int h = threadIdx.x;
    float xx = dtraw[t * NHEADS + h] + dtb[h];
    float sp = (xx > 20.f) ? xx : log1pf(expf(xx));
    dtf[t * NHEADS + h] = sp;
    lnAf[t * NHEADS + h] = -sp * expf(alog[h]);
  }
  for (int c = threadIdx.x; c < CONVCH; c += 256) {
    float acc = cb[c];
#pragma unroll
    for (int k = 0; k < 4; ++k) {
      int tp = tt - 3 + k;
      if (tp >= 0)
        acc += b2f(zx[(size_t)(t - 3 + k) * DINPROJ + DINNER + c]) * cw[c * 4 + k];
    }
    float s = acc / (1.f + expf(-acc));
    unsigned short sb = f2b(s);
    xbc[(size_t)t * CONVCH + c] = sb;
    if (c >= DINNER) bcb[(size_t)t * 256 + (c - DINNER)] = sb;
  }
}

// ---------------- SSD pass 1: intra-chunk (per (b,h,chunk)) ----------------
// r8 (validated): wsL precompute + BWT cooperative transpose.
__global__ __launch_bounds__(256) void ssd_intra(
    const unsigned short* __restrict__ bcb,
    const unsigned short* __restrict__ xbc,
    const float* __restrict__ dtf, const float* __restrict__ lnAf,
    unsigned short* __restrict__ y1buf, unsigned short* __restrict__ SL,
    float* __restrict__ dtot) {
  const int bi = blockIdx.x;           // ((b*32+h)*16 + c), 1024 blocks
  const int c = bi & 15;
  const int h = (bi >> 4) & 31;
  const int b = bi >> 9;
  const int tid = threadIdx.x;
  const int w = tid >> 6, l = tid & 63, r = l & 15, quad = l >> 4;
  const size_t tok0 = (size_t)b * T_SEQ + c * 64;

  __shared__ __align__(16) unsigned short BCs[64 * 264];  // [t][B0..127|C128..255]+pad
  __shared__ __align__(16) unsigned short Xrow[64 * 72];  // [u][p]
  __shared__ __align__(16) unsigned short XTs[64 * 72];   // [p][u]
  __shared__ __align__(16) unsigned short BWT[128 * 72];  // [n][u] = ws[u]*B[u][n]
  __shared__ __align__(16) unsigned short Ms[64 * 72];    // [t][u]
  __shared__ float cumL[64], dtL[64], wsL[64];

#pragma unroll
  for (int i = 0; i < 8; ++i) {
    int idx = tid + i * 256;
    int row = idx >> 5, col = (idx & 31) * 8;
    uint4 v = *(const uint4*)(bcb + (tok0 + row) * 256 + col);
    *(uint4*)(BCs + row * 264 + col) = v;
  }
  // x tile: rows = tokens (coalesced 128B from xbc), cols = p
#pragma unroll
  for (int i = 0; i < 2; ++i) {
    int idx = tid + i * 256;
    int u = idx >> 3, pc = (idx & 7) * 8;
    uint4 v = *(const uint4*)(xbc + (tok0 + u) * CONVCH + h * HEADDIM + pc);
    *(uint4*)(Xrow + u * 72 + pc) = v;
  }
  if (tid < 64) {
    float dt = dtf[(tok0 + tid) * NHEADS + h];
    float v = lnAf[(tok0 + tid) * NHEADS + h];
    dtL[tid] = dt;
#pragma unroll
    for (int off = 1; off < 64; off <<= 1) {
      float u = __shfl_up(v, off, 64);
      if (tid >= off) v += u;
    }
    cumL[tid] = v;
    float tot = __shfl(v, 63, 64);   // scan total, in-wave broadcast
    wsL[tid] = dt * expf(tot - v);   // ws[u] = dt[u]*exp(cum63-cum[u]), once
    if (tid == 63) dtot[bi] = expf(tot);
  }
  __syncthreads();

  // in-LDS transpose: XTs[p][u] = x
#pragma unroll
  for (int i = 0; i < 2; ++i) {
    int idx = tid + i * 256;
    int p = idx >> 3, ug = (idx & 7) * 8;
    unsigned short tA[8];
#pragma unroll
    for (int j = 0; j < 8; ++j) tA[j] = Xrow[(ug + j) * 72 + p];
    *(uint4*)(XTs + p * 72 + ug) = *(uint4*)tA;
  }

  // cooperative B-transpose with ws fold: BWT[n][u] = ws[u]*B[u][n]
  {
    const int n = tid >> 1;
    const int ug = (tid & 1) * 32;
    unsigned short eb[32];
#pragma unroll
    for (int j = 0; j < 32; ++j)
      eb[j] = f2b(b2f(BCs[(ug + j) * 264 + n]) * wsL[ug + j]);
#pragma unroll
    for (int qq = 0; qq < 4; ++qq)
      *(uint4*)(BWT + n * 72 + ug + qq * 8) = *(uint4*)(eb + qq * 8);
  }

  // GEMM1: G = C·B^T  (64x64, K=128)
  f32x4 g[4];
#pragma unroll
  for (int nt = 0; nt < 4; ++nt) g[nt] = f32x4{0.f, 0.f, 0.f, 0.f};
#pragma unroll
  for (int kk = 0; kk < 4; ++kk) {
    bf16x8 afr = *(const bf16x8*)(BCs + (w * 16 + r) * 264 + 128 + kk * 32 + quad * 8);
#pragma unroll
    for (int nt = 0; nt < 4; ++nt) {
      bf16x8 bfr = *(const bf16x8*)(BCs + (nt * 16 + r) * 264 + kk * 32 + quad * 8);
      g[nt] = __builtin_amdgcn_mfma_f32_16x16x32_bf16(afr, bfr, g[nt], 0, 0, 0);
    }
  }
#pragma unroll
  for (int nt = 0; nt < 4; ++nt) {
#pragma unroll
    for (int i = 0; i < 4; ++i) {
      int t_ = w * 16 + quad * 4 + i;
      int u_ = nt * 16 + r;
      float wv = (u_ <= t_) ? expf(cumL[t_] - cumL[u_]) * dtL[u_] : 0.f;
      Ms[t_ * 72 + u_] = f2b(g[nt][i] * wv);
    }
  }
  __syncthreads();   // fences Ms, XTs, BWT writes -> GEMM2/GEMM3 reads

  // GEMM2: Y1 = M·X  (64t x 64p, K=64u)
  f32x4 y1[4];
#pragma unroll
  for (int nt = 0; nt < 4; ++nt) y1[nt] = f32x4{0.f, 0.f, 0.f, 0.f};
#pragma unroll
  for (int kk = 0; kk < 2; ++kk) {
    bf16x8 afr = *(const bf16x8*)(Ms + (w * 16 + r) * 72 + kk * 32 + quad * 8);
#pragma unroll
    for (int nt = 0; nt < 4; ++nt) {
      bf16x8 bfr = *(const bf16x8*)(XTs + (nt * 16 + r) * 72 + kk * 32 + quad * 8);
      y1[nt] = __builtin_amdgcn_mfma_f32_16x16x32_bf16(afr, bfr, y1[nt], 0, 0, 0);
    }
  }
#pragma unroll
  for (int nt = 0; nt < 4; ++nt)
#pragma unroll
    for (int i = 0; i < 4; ++i) {
      int t_ = w * 16 + quad * 4 + i, p_ = nt * 16 + r;
      y1buf[((size_t)bi * 64 + t_) * 64 + p_] = f2b(y1[nt][i]);
    }

  // GEMM3: Slocal[p][n] = sum_u XTs[p][u] * BWT[n][u]  (64p x 128n, K=64u)
  f32x4 sl[8];
#pragma unroll
  for (int nt = 0; nt < 8; ++nt) sl[nt] = f32x4{0.f, 0.f, 0.f, 0.f};
#pragma unroll
  for (int kk = 0; kk < 2; ++kk) {
    bf16x8 afr = *(const bf16x8*)(XTs + (w * 16 + r) * 72 + kk * 32 + quad * 8);
#pragma unroll
    for (int nt = 0; nt < 8; ++nt) {
      bf16x8 bfr = *(const bf16x8*)(BWT + (nt * 16 + r) * 72 + kk * 32 + quad * 8);
      sl[nt] = __builtin_amdgcn_mfma_f32_16x16x32_bf16(afr, bfr, sl[nt], 0, 0, 0);
    }
  }
#pragma unroll
  for (int nt = 0; nt < 8; ++nt)
#pragma unroll
    for (int i = 0; i < 4; ++i) {
      int p_ = w * 16 + quad * 4 + i, n_ = nt * 16 + r;
      SL[((size_t)bi * 64 + p_) * 128 + n_] = f2b(sl[nt][i]);
    }
}

// ---------------- SSD pass 2: chunk-state recurrence (in-place Slocal -> Spre) --------
__global__ void ssd_state(unsigned short* __restrict__ SL,
                          const float* __restrict__ dtot) {
  int gidx = blockIdx.x * 256 + threadIdx.x;   // 131072 = 64bh * 64p * 32(n/4)
  int n4 = (gidx & 31) * 4;
  int p = (gidx >> 5) & 63;
  int bh = gidx >> 11;
  float sx = 0.f, sy = 0.f, sz = 0.f, sw = 0.f;
  for (int c = 0; c < NCHUNK; ++c) {
    size_t off = ((size_t)(bh * 16 + c) * 64 + p) * 128 + n4;
    uint2 lv = *(uint2*)(SL + off);
    float d = dtot[bh * 16 + c];
    uint2 sv;
    sv.x = (unsigned)f2b(sx) | ((unsigned)f2b(sy) << 16);
    sv.y = (unsigned)f2b(sz) | ((unsigned)f2b(sw) << 16);
    *(uint2*)(SL + off) = sv;           // state BEFORE chunk c
    sx = d * sx + b2f(lv.x & 0xffff);
    sy = d * sy + b2f(lv.x >> 16);
    sz = d * sz + b2f(lv.y & 0xffff);
    sw = d * sw + b2f(lv.y >> 16);
  }
}

// ---------------- SSD pass 3: inter-chunk + combine + gate ----------------
// r18: accumulates per-token sum-of-squares of the gated f32 output into
// ssq[tok] (2 shfl + 1 atomicAdd per token per block) for the fused RMSNorm
// in gemm<1>'s epilogue.
__global__ __launch_bounds__(256) void ssd_inter(
    const unsigned short* __restrict__ bcb,
    const unsigned short* __restrict__ SL,       // holds Spre now
    const unsigned short* __restrict__ y1buf,
    const unsigned short* __restrict__ xbc,
    const unsigned short* __restrict__ zx,
    const float* __restrict__ lnAf,
    const float* __restrict__ Dw,
    unsigned short* __restrict__ yg,
    float* __restrict__ ssq) {
  const int bi = blockIdx.x;
  const int c = bi & 15, h = (bi >> 4) & 31, b = bi >> 9;
  const int tid = threadIdx.x;
  const int w = tid >> 6, l = tid & 63, r = l & 15, quad = l >> 4;
  const size_t tok0 = (size_t)b * T_SEQ + c * 64;

  __shared__ __align__(16) unsigned short Cs[64 * 136];
  __shared__ __align__(16) unsigned short Sp[64 * 136];
  __shared__ __align__(16) float Yf[64 * 68];
  __shared__ float cumL[64];

#pragma unroll
  for (int i = 0; i < 4; ++i) {
    int idx = tid + i * 256;
    int row = idx >> 4, col = (idx & 15) * 8;
    uint4 v = *(const uint4*)(bcb + (tok0 + row) * 256 + 128 + col);
    *(uint4*)(Cs + row * 136 + col) = v;
    uint4 s = *(const uint4*)(SL + ((size_t)bi * 64 + row) * 128 + col);
    *(uint4*)(Sp + row * 136 + col) = s;
  }
  if (tid < 64) {
    float v = lnAf[(tok0 + tid) * NHEADS + h];
#pragma unroll
    for (int off = 1; off < 64; off <<= 1) {
      float u = __shfl_up(v, off, 64);
      if (tid >= off) v += u;
    }
    cumL[tid] = v;
  }
  __syncthreads();

  // Yi[t][p] = sum_n C[t][n]*Spre[p][n]  (K=128)
  f32x4 yi[4];
#pragma unroll
  for (int nt = 0; nt < 4; ++nt) yi[nt] = f32x4{0.f, 0.f, 0.f, 0.f};
#pragma unroll
  for (int kk = 0; kk < 4; ++kk) {
    bf16x8 afr = *(const bf16x8*)(Cs + (w * 16 + r) * 136 + kk * 32 + quad * 8);
#pragma unroll
    for (int nt = 0; nt < 4; ++nt) {
      bf16x8 bfr = *(const bf16x8*)(Sp + (nt * 16 + r) * 136 + kk * 32 + quad * 8);
      yi[nt] = __builtin_amdgcn_mfma_f32_16x16x32_bf16(afr, bfr, yi[nt], 0, 0, 0);
    }
  }
#pragma unroll
  for (int nt = 0; nt < 4; ++nt)
#pragma unroll
    for (int i = 0; i < 4; ++i) {
      int t_ = w * 16 + quad * 4 + i, p_ = nt * 16 + r;
      float y1 = b2f(y1buf[((size_t)bi * 64 + t_) * 64 + p_]);
      Yf[t_ * 68 + p_] = y1 + expf(cumL[t_]) * yi[nt][i];
    }
  __syncthreads();

  // combine: y = Yf + D*x, gate with silu(z), write yg + accumulate ssq
  const float Dh = Dw[h];
  const int t_ = tid >> 2, pg = (tid & 3) * 16;
  const size_t tok = tok0 + t_;
  union { uint4 q[2]; unsigned short u[16]; } xv, zv, ov;
  xv.q[0] = *(const uint4*)(xbc + tok * CONVCH + h * 64 + pg);
  xv.q[1] = *(const uint4*)(xbc + tok * CONVCH + h * 64 + pg + 8);
  zv.q[0] = *(const uint4*)(zx + tok * DINPROJ + h * 64 + pg);
  zv.q[1] = *(const uint4*)(zx + tok * DINPROJ + h * 64 + pg + 8);
  float ssf = 0.f;
#pragma unroll
  for (int j = 0; j < 16; ++j) {
    float y = Yf[t_ * 68 + pg + j] + Dh * b2f(xv.u[j]);
    float zf = b2f(zv.u[j]);
    float yg_f = y * (zf / (1.f + expf(-zf)));
    ov.u[j] = f2b(yg_f);
    ssf += yg_f * yg_f;
  }
  *(uint4*)(yg + tok * DINNER + h * 64 + pg) = ov.q[0];
  *(uint4*)(yg + tok * DINNER + h * 64 + pg + 8) = ov.q[1];
  // reduce the 4 lanes of this token, one atomic per token per block
  ssf += __shfl_xor(ssf, 1, 64);
  ssf += __shfl_xor(ssf, 2, 64);
  if ((tid & 3) == 0) atomicAdd(&ssq[tok], ssf);
}

// ---------------- final RMSNorm over 1024 ----------------
__global__ void rmsfinal_k(const float* __restrict__ hf,
                           const float* __restrict__ w,
                           unsigned short* __restrict__ out) {
  int t = blockIdx.x;
  int base = threadIdx.x * 4;
  float4 v = *(const float4*)(hf + (size_t)t * DIM + base);
  float ss = v.x * v.x + v.y * v.y + v.z * v.z + v.w * v.w;
#pragma unroll
  for (int o = 32; o > 0; o >>= 1) ss += __shfl_xor(ss, o, 64);
  __shared__ float red[4];
  if ((threadIdx.x & 63) == 0) red[threadIdx.x >> 6] = ss;
  __syncthreads();
  ss = red[0] + red[1] + red[2] + red[3];
  float scale = rsqrtf(ss * (1.f / DIM) + EPS_F);
  out[(size_t)t * DIM + base + 0] = f2b(v.x * scale * w[base + 0]);
  out[(size_t)t * DIM + base + 1] = f2b(v.y * scale * w[base + 1]);
  out[(size_t)t * DIM + base + 2] = f2b(v.z * scale * w[base + 2]);
  out[(size_t)t * DIM + base + 3] = f2b(v.w * scale * w[base + 3]);
}

extern "C" void kernel_launch(void* const* d_in, const int* in_sizes, int n_in,
                              void* d_out, int out_size, void* d_ws, size_t ws_size,
                              hipStream_t stream) {
  const int*   x    = (const int*)d_in[0];
  const float* emb  = (const float*)d_in[1];
  const float* Wp   = (const float*)d_in[2];
  const float* cw   = (const float*)d_in[3];
  const float* cb   = (const float*)d_in[4];
  const float* dtb  = (const float*)d_in[5];
  const float* alog = (const float*)d_in[6];
  const float* Dw   = (const float*)d_in[7];
  const float* gw   = (const float*)d_in[8];
  const float* Wo   = (const float*)d_in[9];
  const float* fnw  = (const float*)d_in[10];

  char* w = (char*)d_ws;
  auto alloc = [&](size_t bytes) {
    char* p = w; w += (bytes + 255) & ~(size_t)255; return p;
  };
  float* h_f32          = (float*)alloc((size_t)BT * DIM * 4);
  unsigned short* hb    = (unsigned short*)alloc((size_t)BT * DIM * 2);
  unsigned short* zx    = (unsigned short*)alloc((size_t)BT * DINPROJ * 2);
  float* dtraw          = (float*)alloc((size_t)BT * NHEADS * 4);
  float* dtf            = (float*)alloc((size_t)BT * NHEADS * 4);
  float* lnAf           = (float*)alloc((size_t)BT * NHEADS * 4);
  unsigned short* xbc   = (unsigned short*)alloc((size_t)BT * CONVCH * 2);
  unsigned short* bcb   = (unsigned short*)alloc((size_t)BT * 256 * 2);
  unsigned short* SL    = (unsigned short*)alloc((size_t)1024 * 64 * 128 * 2);
  unsigned short* y1buf = (unsigned short*)alloc((size_t)1024 * 64 * 64 * 2);
  float* dtot           = (float*)alloc((size_t)1024 * 4);
  unsigned short* yg    = (unsigned short*)alloc((size_t)BT * DINNER * 2);
  float* ssq            = (float*)alloc((size_t)BT * 4);
  unsigned short* hn    = (unsigned short*)alloc((size_t)BT * DIM * 2);
  unsigned short* Wp_b  = (unsigned short*)alloc((size_t)2 * DINPROJ * DIM * 2);
  unsigned short* Wo_b  = (unsigned short*)alloc((size_t)2 * DIM * DINNER * 2);
  unsigned short* emb_b = (unsigned short*)alloc((size_t)256 * DIM * 2 + 256);

  // fused prologue: 3x weight cvt (gw folded into Wo) + embed in ONE launch
  prologue_k<<<PRO_BLK, 256, 0, stream>>>(Wp, Wo, emb, gw, Wp_b, Wo_b, emb_b, x, h_f32, hb);

  for (int l = 0; l < 2; ++l) {
    const unsigned short* Wpl = Wp_b + (size_t)l * DINPROJ * DIM;
    const unsigned short* Wol = Wo_b + (size_t)l * DIM * DINNER;
    const float* cwl   = cw + (size_t)l * CONVCH * 4;
    const float* cbl   = cb + (size_t)l * CONVCH;
    const float* dtbl  = dtb + l * NHEADS;
    const float* alogl = alog + l * NHEADS;
    const float* Dwl   = Dw + l * NHEADS;

    gemm_bt<0, 128, 128, 32><<<dim3(35, 16), 256, 0, stream>>>(hb, Wpl, BT, DINPROJ, DIM, zx, dtraw, nullptr, nullptr);
    conv_k<<<BT, 256, 0, stream>>>(zx, cwl, cbl, xbc, bcb, dtraw, dtbl, alogl, dtf, lnAf, ssq);
    ssd_intra<<<1024, 256, 0, stream>>>(bcb, xbc, dtf, lnAf, y1buf, SL, dtot);
    ssd_state<<<512, 256, 0, stream>>>(SL, dtot);
    ssd_inter<<<1024, 256, 0, stream>>>(bcb, SL, y1buf, xbc, zx, lnAf, Dwl, yg, ssq);
    gemm_bt<1, 64, 64, 128><<<dim3(16, 32), 256, 0, stream>>>(yg, Wol, BT, DIM, DINNER, nullptr, h_f32, hb, ssq);
  }

  rmsfinal_k<<<BT, 256, 0, stream>>>(h_f32, fnw, hn);
  gemm_bt<2, 64, 64, 128><<<dim3(4, 32), 256, 0, stream>>>(hn, emb_b, BT, 256, DIM,
                                                           nullptr, (float*)d_out, nullptr, nullptr);
}